// Round 3
// baseline (1087.556 us; speedup 1.0000x reference)
//
#include <hip/hip_runtime.h>

#define B_   2
#define S_   2048
#define D_   4096
#define H_   32
#define KVH_ 8
#define HD_  128
#define NE_  6144   // (KVH*2+H)*HD

using f32x4  = __attribute__((ext_vector_type(4))) float;
using bf16x8 = __attribute__((ext_vector_type(8))) __bf16;

__device__ __forceinline__ unsigned short f2bf(float f) {
  union { float f; unsigned u; } v; v.f = f;
  unsigned r = v.u + 0x7FFFu + ((v.u >> 16) & 1u);
  return (unsigned short)(r >> 16);
}
__device__ __forceinline__ float bf2f(unsigned short h) {
  union { unsigned u; float f; } v; v.u = ((unsigned)h) << 16; return v.f;
}
__device__ __forceinline__ bf16x8 ld8(const unsigned short* p) {
  return *reinterpret_cast<const bf16x8*>(p);
}
__device__ __forceinline__ void cp16(const void* g, void* l) {
  __builtin_amdgcn_global_load_lds(
      (const __attribute__((address_space(1))) void*)g,
      (__attribute__((address_space(3))) void*)l, 16, 0, 0);
}

// ---------------------------------------------------------------------------
// fp32 -> bf16 (RNE), 4 elems/thread. n must be divisible by 4.
// ---------------------------------------------------------------------------
__global__ __launch_bounds__(256) void cvt_f32_bf16(
    const float* __restrict__ in, unsigned short* __restrict__ out, int n4)
{
  int i = blockIdx.x * 256 + threadIdx.x;
  if (i >= n4) return;
  f32x4 v = *reinterpret_cast<const f32x4*>(in + (size_t)i * 4);
  ushort4 o;
  o.x = f2bf(v[0]); o.y = f2bf(v[1]); o.z = f2bf(v[2]); o.w = f2bf(v[3]);
  *reinterpret_cast<ushort4*>(out + (size_t)i * 4) = o;
}

// ---------------------------------------------------------------------------
// C[M,N] = A[M,K] * B[N,K]^T  (A,B bf16 bits; fp32 accum; OutT = ushort|float)
// 128x128 tile, BK=64, 4 waves (2x2), 16x16x32 bf16 MFMA.
// ---------------------------------------------------------------------------
template <typename OutT>
__global__ __launch_bounds__(256) void gemm_bt(
    const unsigned short* __restrict__ A,
    const unsigned short* __restrict__ Bw,
    OutT* __restrict__ C,
    int M, int N, int K)
{
  __shared__ __align__(16) unsigned short As[128 * 64];
  __shared__ __align__(16) unsigned short Bs[128 * 64];
  const int tid  = threadIdx.x;
  const int lane = tid & 63;
  const int wave = tid >> 6;
  const int wr = wave >> 1, wc = wave & 1;
  const int row0 = blockIdx.y * 128;
  const int col0 = blockIdx.x * 128;
  const int lr = lane & 15;
  const int lk = (lane >> 4) * 8;

  f32x4 acc[4][4];
#pragma unroll
  for (int m = 0; m < 4; ++m)
#pragma unroll
    for (int n = 0; n < 4; ++n) acc[m][n] = (f32x4){0.f, 0.f, 0.f, 0.f};

  for (int k0 = 0; k0 < K; k0 += 64) {
    __syncthreads();
#pragma unroll
    for (int i = 0; i < 4; ++i) {
      const int off = i * 2048 + tid * 8;   // element offset in 128x64 tile
      const int r = off >> 6, c = off & 63;
      cp16(A  + (size_t)(row0 + r) * K + (k0 + c), As + i * 2048 + wave * 512);
      cp16(Bw + (size_t)(col0 + r) * K + (k0 + c), Bs + i * 2048 + wave * 512);
    }
    __syncthreads();
#pragma unroll
    for (int kk = 0; kk < 2; ++kk) {
      bf16x8 af[4], bfr[4];
#pragma unroll
      for (int m = 0; m < 4; ++m)
        af[m] = ld8(As + (wr * 64 + m * 16 + lr) * 64 + kk * 32 + lk);
#pragma unroll
      for (int n = 0; n < 4; ++n)
        bfr[n] = ld8(Bs + (wc * 64 + n * 16 + lr) * 64 + kk * 32 + lk);
#pragma unroll
      for (int m = 0; m < 4; ++m)
#pragma unroll
        for (int n = 0; n < 4; ++n)
          acc[m][n] = __builtin_amdgcn_mfma_f32_16x16x32_bf16(af[m], bfr[n], acc[m][n], 0, 0, 0);
    }
  }
  const int orow = (lane >> 4) * 4;
#pragma unroll
  for (int m = 0; m < 4; ++m) {
    const int gr0 = row0 + wr * 64 + m * 16 + orow;
#pragma unroll
    for (int n = 0; n < 4; ++n) {
      const int gc = col0 + wc * 64 + n * 16 + lr;
#pragma unroll
      for (int r = 0; r < 4; ++r) {
        float val = acc[m][n][r];
        if constexpr (sizeof(OutT) == 2)
          C[(size_t)(gr0 + r) * N + gc] = f2bf(val);
        else
          C[(size_t)(gr0 + r) * N + gc] = val;
      }
    }
  }
}

// ---------------------------------------------------------------------------
// Split fused[B,S,48,128] (per kv-group: q0 q1 q2 q3 k v) into
//   Qr[B,H,S,128] (rope), Kr[B,KVH,S,128] (rope), Vt[B,KVH,128,S] (transposed)
// One thread per (b,s,e,d), d in [0,64): handles elems d and d+64.
// ---------------------------------------------------------------------------
__global__ __launch_bounds__(256) void rope_scatter(
    const unsigned short* __restrict__ fused,
    unsigned short* __restrict__ Qr,
    unsigned short* __restrict__ Kr,
    unsigned short* __restrict__ Vt)
{
  int idx = blockIdx.x * 256 + threadIdx.x;  // [0, B*S*48*64)
  int d = idx & 63;
  int t = idx >> 6;
  int e = t % 48;
  int bs = t / 48;
  int s = bs % S_;
  int b = bs / S_;
  int kvh = e / 6, j = e % 6;
  const unsigned short* src = fused + (size_t)bs * NE_ + e * 128;
  unsigned short u1 = src[d];
  unsigned short u2 = src[d + 64];
  if (j == 5) {  // V: transposed store
    size_t base = (size_t)(b * KVH_ + kvh) * HD_ * S_;
    Vt[base + (size_t)d * S_ + s]        = u1;
    Vt[base + (size_t)(d + 64) * S_ + s] = u2;
  } else {
    float x1 = bf2f(u1), x2 = bf2f(u2);
    float inv = __expf(-(float)d * (9.2103403719761836f / 64.0f)); // 10000^(-d/64)
    float ang = (float)s * inv;
    float sn, c;
    sincosf(ang, &sn, &c);   // precise arg reduction (ang up to ~2047 rad)
    float o1 = x1 * c - x2 * sn;
    float o2 = x2 * c + x1 * sn;
    unsigned short* dst;
    if (j == 4) dst = Kr + ((size_t)(b * KVH_ + kvh) * S_ + s) * HD_;
    else        dst = Qr + ((size_t)(b * H_ + kvh * 4 + j) * S_ + s) * HD_;
    dst[d]      = f2bf(o1);
    dst[d + 64] = f2bf(o2);
  }
}

// ---------------------------------------------------------------------------
// Causal GQA flash attention.
// Block = (qb, h, b): 64 q-rows, 4 waves x 16 rows. KVBLK=64.
// K_lds [64][128], V_lds [128][64] (k-contig), P via per-wave LDS roundtrip.
// ---------------------------------------------------------------------------
__global__ __launch_bounds__(256) void attn_fwd(
    const unsigned short* __restrict__ Qr,
    const unsigned short* __restrict__ Kr,
    const unsigned short* __restrict__ Vt,
    unsigned short* __restrict__ O)
{
  __shared__ __align__(16) unsigned short Kld[64 * 128];
  __shared__ __align__(16) unsigned short Vld[128 * 64];
  __shared__ __align__(16) unsigned short Pld[4][16 * 64];

  const int tid  = threadIdx.x;
  const int lane = tid & 63;
  const int wave = tid >> 6;
  const int qb = blockIdx.x;   // 0..31
  const int h  = blockIdx.y;   // 0..31
  const int b  = blockIdx.z;   // 0..1
  const int kvh = h >> 2;
  const int lr = lane & 15;
  const int lk = (lane >> 4) * 8;
  const int orow = (lane >> 4) * 4;

  const unsigned short* qbase =
      Qr + ((size_t)(b * H_ + h) * S_ + qb * 64 + wave * 16 + lr) * HD_;
  bf16x8 qf[4];
#pragma unroll
  for (int t = 0; t < 4; ++t) qf[t] = ld8(qbase + t * 32 + lk);

  f32x4 acc_o[8];
#pragma unroll
  for (int dt = 0; dt < 8; ++dt) acc_o[dt] = (f32x4){0.f, 0.f, 0.f, 0.f};
  float mrow[4], lrow[4];
#pragma unroll
  for (int r = 0; r < 4; ++r) { mrow[r] = -1e30f; lrow[r] = 0.f; }

  const float scale = 0.08838834764831845f;  // 1/sqrt(128)
  const unsigned short* Kb = Kr + (size_t)(b * KVH_ + kvh) * S_ * HD_;
  const unsigned short* Vb = Vt + (size_t)(b * KVH_ + kvh) * HD_ * S_;

  for (int kb = 0; kb <= qb; ++kb) {
    __syncthreads();
#pragma unroll
    for (int i = 0; i < 4; ++i) {
      const int off = i * 2048 + tid * 8;
      cp16(Kb + (size_t)(kb * 64 + (off >> 7)) * HD_ + (off & 127),
           Kld + i * 2048 + wave * 512);
      cp16(Vb + (size_t)(off >> 6) * S_ + kb * 64 + (off & 63),
           Vld + i * 2048 + wave * 512);
    }
    __syncthreads();

    // S = Q K^T for this wave's 16 rows x 64 cols
    f32x4 accs[4];
#pragma unroll
    for (int kt = 0; kt < 4; ++kt) accs[kt] = (f32x4){0.f, 0.f, 0.f, 0.f};
#pragma unroll
    for (int t = 0; t < 4; ++t) {
#pragma unroll
      for (int kt = 0; kt < 4; ++kt) {
        bf16x8 kf = ld8(Kld + (kt * 16 + lr) * 128 + t * 32 + lk);
        accs[kt] = __builtin_amdgcn_mfma_f32_16x16x32_bf16(qf[t], kf, accs[kt], 0, 0, 0);
      }
    }

    const bool last = (kb == qb);
    float sv[4][4];
#pragma unroll
    for (int r = 0; r < 4; ++r) {
      const int qg = qb * 64 + wave * 16 + orow + r;
#pragma unroll
      for (int kt = 0; kt < 4; ++kt) {
        float v = accs[kt][r] * scale;
        int kg = kb * 64 + kt * 16 + lr;
        if (last && kg > qg) v = -1e30f;
        sv[r][kt] = v;
      }
    }

    float mnew[4], corr[4];
#pragma unroll
    for (int r = 0; r < 4; ++r) {
      float mx = fmaxf(fmaxf(sv[r][0], sv[r][1]), fmaxf(sv[r][2], sv[r][3]));
#pragma unroll
      for (int msk = 8; msk >= 1; msk >>= 1) mx = fmaxf(mx, __shfl_xor(mx, msk, 64));
      mnew[r] = fmaxf(mrow[r], mx);
      corr[r] = __expf(mrow[r] - mnew[r]);
      mrow[r] = mnew[r];
    }
#pragma unroll
    for (int r = 0; r < 4; ++r) {
      float su = 0.f;
#pragma unroll
      for (int kt = 0; kt < 4; ++kt) {
        float p = __expf(sv[r][kt] - mnew[r]);
        su += p;
        Pld[wave][(orow + r) * 64 + kt * 16 + lr] = f2bf(p);
      }
#pragma unroll
      for (int msk = 8; msk >= 1; msk >>= 1) su += __shfl_xor(su, msk, 64);
      lrow[r] = lrow[r] * corr[r] + su;
    }
#pragma unroll
    for (int dt = 0; dt < 8; ++dt)
#pragma unroll
      for (int r = 0; r < 4; ++r) acc_o[dt][r] *= corr[r];

    // Compiler fence: Pld written as ushort, read as bf16x8 below (TBAA).
    asm volatile("" ::: "memory");

    // O += P V   (P: [16q x 64k] in Pld, V: Vld[d][k] k-contig)
#pragma unroll
    for (int kc = 0; kc < 2; ++kc) {
      bf16x8 pf = ld8(&Pld[wave][lr * 64 + kc * 32 + lk]);
#pragma unroll
      for (int dt = 0; dt < 8; ++dt) {
        bf16x8 vf = ld8(Vld + (dt * 16 + lr) * 64 + kc * 32 + lk);
        acc_o[dt] = __builtin_amdgcn_mfma_f32_16x16x32_bf16(pf, vf, acc_o[dt], 0, 0, 0);
      }
    }
  }

#pragma unroll
  for (int r = 0; r < 4; ++r) {
    float inv = 1.f / lrow[r];
    size_t rowoff =
        (size_t)(b * S_ + qb * 64 + wave * 16 + orow + r) * (H_ * HD_) + h * HD_;
#pragma unroll
    for (int dt = 0; dt < 8; ++dt)
      O[rowoff + dt * 16 + lr] = f2bf(acc_o[dt][r] * inv);
  }
}

// Diagnostic: if ws_size is too small, fill fp32 output with sentinel 12345.
__global__ void fill_sentinel(float* __restrict__ O, int n) {
  int i = blockIdx.x * 256 + threadIdx.x;
  if (i < n) O[i] = 12345.0f;
}

// ---------------------------------------------------------------------------
extern "C" void kernel_launch(void* const* d_in, const int* in_sizes, int n_in,
                              void* d_out, int out_size, void* d_ws, size_t ws_size,
                              hipStream_t stream) {
  const float* hidden = (const float*)d_in[0]; // [B,S,D] fp32
  const float* wqkv   = (const float*)d_in[1]; // [6144,4096] fp32
  const float* wdense = (const float*)d_in[2]; // [4096,4096] fp32
  float* out = (float*)d_out;                  // [B,S,4096] fp32

  const size_t NEED = 134217728;
  if (ws_size < NEED) {
    fill_sentinel<<<dim3((out_size + 255) / 256), dim3(256), 0, stream>>>(out, out_size);
    return;
  }

  char* ws = (char*)d_ws;
  // Phase 1 layout
  unsigned short* Hb    = (unsigned short*)(ws);                 // 33,554,432 B
  unsigned short* Wqb   = (unsigned short*)(ws + 33554432);      // 50,331,648 B
  unsigned short* fused = (unsigned short*)(ws + 83886080);      // 50,331,648 B
  // Phase 2 layout (after GEMM1: Hb/Wqb dead)
  unsigned short* Qr    = (unsigned short*)(ws);                 // 33,554,432 B
  unsigned short* Kr    = (unsigned short*)(ws + 33554432);      //  8,388,608 B
  unsigned short* Vt    = (unsigned short*)(ws + 41943040);      //  8,388,608 B
  unsigned short* Wdb   = (unsigned short*)(ws + 50331648);      // 33,554,432 B
  unsigned short* attn_out = (unsigned short*)(ws + 83886080);   // 33,554,432 B (over fused)

  const int nH = B_ * S_ * D_;      // 16,777,216
  const int nQ = NE_ * D_;          // 25,165,824
  const int nD = D_ * D_;           // 16,777,216

  cvt_f32_bf16<<<dim3(nH / 4 / 256), dim3(256), 0, stream>>>(hidden, Hb, nH / 4);
  cvt_f32_bf16<<<dim3(nQ / 4 / 256), dim3(256), 0, stream>>>(wqkv, Wqb, nQ / 4);

  gemm_bt<unsigned short><<<dim3(NE_ / 128, (B_ * S_) / 128), dim3(256), 0, stream>>>(
      Hb, Wqb, fused, B_ * S_, NE_, D_);

  cvt_f32_bf16<<<dim3(nD / 4 / 256), dim3(256), 0, stream>>>(wdense, Wdb, nD / 4);

  rope_scatter<<<dim3((B_ * S_ * 48 * 64) / 256), dim3(256), 0, stream>>>(
      fused, Qr, Kr, Vt);

  attn_fwd<<<dim3(S_ / 64, H_, B_), dim3(256), 0, stream>>>(Qr, Kr, Vt, attn_out);

  gemm_bt<float><<<dim3(D_ / 128, (B_ * S_) / 128), dim3(256), 0, stream>>>(
      attn_out, Wdb, out, B_ * S_, D_, D_);
}

// Round 4
// 729.799 us; speedup vs baseline: 1.4902x; 1.4902x over previous
//
#include <hip/hip_runtime.h>

#define B_   2
#define S_   2048
#define D_   4096
#define H_   32
#define KVH_ 8
#define HD_  128
#define NE_  6144   // (KVH*2+H)*HD

using f32x4  = __attribute__((ext_vector_type(4))) float;
using bf16x8 = __attribute__((ext_vector_type(8))) __bf16;

__device__ __forceinline__ unsigned short f2bf(float f) {
  union { float f; unsigned u; } v; v.f = f;
  unsigned r = v.u + 0x7FFFu + ((v.u >> 16) & 1u);
  return (unsigned short)(r >> 16);
}
__device__ __forceinline__ float bf2f(unsigned short h) {
  union { unsigned u; float f; } v; v.u = ((unsigned)h) << 16; return v.f;
}
__device__ __forceinline__ bf16x8 ld8(const unsigned short* p) {
  return *reinterpret_cast<const bf16x8*>(p);
}
__device__ __forceinline__ bf16x8 ld8b(const void* base, int byte_off) {
  return *reinterpret_cast<const bf16x8*>((const char*)base + byte_off);
}
__device__ __forceinline__ void cp16(const void* g, void* l) {
  __builtin_amdgcn_global_load_lds(
      (const __attribute__((address_space(1))) void*)g,
      (__attribute__((address_space(3))) void*)l, 16, 0, 0);
}

// ---------------------------------------------------------------------------
// fp32 -> bf16 (RNE), 4 elems/thread.
// ---------------------------------------------------------------------------
__global__ __launch_bounds__(256) void cvt_f32_bf16(
    const float* __restrict__ in, unsigned short* __restrict__ out, int n4)
{
  int i = blockIdx.x * 256 + threadIdx.x;
  if (i >= n4) return;
  f32x4 v = *reinterpret_cast<const f32x4*>(in + (size_t)i * 4);
  ushort4 o;
  o.x = f2bf(v[0]); o.y = f2bf(v[1]); o.z = f2bf(v[2]); o.w = f2bf(v[3]);
  *reinterpret_cast<ushort4*>(out + (size_t)i * 4) = o;
}

// ---------------------------------------------------------------------------
// C[M,N] = A[M,K] * B[N,K]^T  (A,B bf16 bits; fp32 accum; OutT = ushort|float)
// 128x128 tile, BK=64, 4 waves (2x2), 16x16x32 bf16 MFMA.
// ---------------------------------------------------------------------------
template <typename OutT>
__global__ __launch_bounds__(256) void gemm_bt(
    const unsigned short* __restrict__ A,
    const unsigned short* __restrict__ Bw,
    OutT* __restrict__ C,
    int M, int N, int K)
{
  __shared__ __align__(16) unsigned short As[128 * 64];
  __shared__ __align__(16) unsigned short Bs[128 * 64];
  const int tid  = threadIdx.x;
  const int lane = tid & 63;
  const int wave = tid >> 6;
  const int wr = wave >> 1, wc = wave & 1;
  const int row0 = blockIdx.y * 128;
  const int col0 = blockIdx.x * 128;
  const int lr = lane & 15;
  const int lk = (lane >> 4) * 8;

  f32x4 acc[4][4];
#pragma unroll
  for (int m = 0; m < 4; ++m)
#pragma unroll
    for (int n = 0; n < 4; ++n) acc[m][n] = (f32x4){0.f, 0.f, 0.f, 0.f};

  for (int k0 = 0; k0 < K; k0 += 64) {
    __syncthreads();
#pragma unroll
    for (int i = 0; i < 4; ++i) {
      const int off = i * 2048 + tid * 8;   // element offset in 128x64 tile
      const int r = off >> 6, c = off & 63;
      cp16(A  + (size_t)(row0 + r) * K + (k0 + c), As + i * 2048 + wave * 512);
      cp16(Bw + (size_t)(col0 + r) * K + (k0 + c), Bs + i * 2048 + wave * 512);
    }
    __syncthreads();
#pragma unroll
    for (int kk = 0; kk < 2; ++kk) {
      bf16x8 af[4], bfr[4];
#pragma unroll
      for (int m = 0; m < 4; ++m)
        af[m] = ld8(As + (wr * 64 + m * 16 + lr) * 64 + kk * 32 + lk);
#pragma unroll
      for (int n = 0; n < 4; ++n)
        bfr[n] = ld8(Bs + (wc * 64 + n * 16 + lr) * 64 + kk * 32 + lk);
#pragma unroll
      for (int m = 0; m < 4; ++m)
#pragma unroll
        for (int n = 0; n < 4; ++n)
          acc[m][n] = __builtin_amdgcn_mfma_f32_16x16x32_bf16(af[m], bfr[n], acc[m][n], 0, 0, 0);
    }
  }
  const int orow = (lane >> 4) * 4;
#pragma unroll
  for (int m = 0; m < 4; ++m) {
    const int gr0 = row0 + wr * 64 + m * 16 + orow;
#pragma unroll
    for (int n = 0; n < 4; ++n) {
      const int gc = col0 + wc * 64 + n * 16 + lr;
#pragma unroll
      for (int r = 0; r < 4; ++r) {
        float val = acc[m][n][r];
        if constexpr (sizeof(OutT) == 2)
          C[(size_t)(gr0 + r) * N + gc] = f2bf(val);
        else
          C[(size_t)(gr0 + r) * N + gc] = val;
      }
    }
  }
}

// ---------------------------------------------------------------------------
// Split fused[B,S,48,128] (per kv-group: q0 q1 q2 q3 k v) into
//   Qr[B,H,S,128] (rope), Kr[B,KVH,S,128] (rope), Vt[B,KVH,128,S] (transposed)
// ---------------------------------------------------------------------------
__global__ __launch_bounds__(256) void rope_scatter(
    const unsigned short* __restrict__ fused,
    unsigned short* __restrict__ Qr,
    unsigned short* __restrict__ Kr,
    unsigned short* __restrict__ Vt)
{
  int idx = blockIdx.x * 256 + threadIdx.x;  // [0, B*S*48*64)
  int d = idx & 63;
  int t = idx >> 6;
  int e = t % 48;
  int bs = t / 48;
  int s = bs % S_;
  int b = bs / S_;
  int kvh = e / 6, j = e % 6;
  const unsigned short* src = fused + (size_t)bs * NE_ + e * 128;
  unsigned short u1 = src[d];
  unsigned short u2 = src[d + 64];
  if (j == 5) {  // V: transposed store
    size_t base = (size_t)(b * KVH_ + kvh) * HD_ * S_;
    Vt[base + (size_t)d * S_ + s]        = u1;
    Vt[base + (size_t)(d + 64) * S_ + s] = u2;
  } else {
    float x1 = bf2f(u1), x2 = bf2f(u2);
    float inv = __expf(-(float)d * (9.2103403719761836f / 64.0f)); // 10000^(-d/64)
    float ang = (float)s * inv;
    float sn, c;
    sincosf(ang, &sn, &c);
    float o1 = x1 * c - x2 * sn;
    float o2 = x2 * c + x1 * sn;
    unsigned short* dst;
    if (j == 4) dst = Kr + ((size_t)(b * KVH_ + kvh) * S_ + s) * HD_;
    else        dst = Qr + ((size_t)(b * H_ + kvh * 4 + j) * S_ + s) * HD_;
    dst[d]      = f2bf(o1);
    dst[d + 64] = f2bf(o2);
  }
}

// ---------------------------------------------------------------------------
// Causal GQA flash attention, bank-conflict-free via XOR swizzle, load-balanced.
// Block = (bx, h, b): handles q-tiles qb=bx and qb=31-bx (33 KV-iters each).
// 4 waves x 16 q-rows. KVBLK=64.
// LDS: Kld [64][128] swz, Vld [128][64] swz, Pld [4][16][64] swz. 40960 B.
// Swizzle: byte ^= (row&7)<<4 (involution); K/V staged via global_load_lds
// with inverse-swizzled global SOURCE column (linear LDS dest), read swizzled.
// ---------------------------------------------------------------------------
__global__ __launch_bounds__(256) void attn_fwd(
    const unsigned short* __restrict__ Qr,
    const unsigned short* __restrict__ Kr,
    const unsigned short* __restrict__ Vt,
    unsigned short* __restrict__ O)
{
  __shared__ __align__(16) unsigned short Kld[64 * 128];
  __shared__ __align__(16) unsigned short Vld[128 * 64];
  __shared__ __align__(16) unsigned short Pld[4][16 * 64];

  const int tid  = threadIdx.x;
  const int lane = tid & 63;
  const int wave = tid >> 6;
  const int bx = blockIdx.x;   // 0..15
  const int h  = blockIdx.y;   // 0..31
  const int b  = blockIdx.z;   // 0..1
  const int kvh = h >> 2;
  const int lr = lane & 15;
  const int lk = (lane >> 4) * 8;
  const int orow = (lane >> 4) * 4;

  const float scale = 0.08838834764831845f;  // 1/sqrt(128)
  const unsigned short* Kb = Kr + (size_t)(b * KVH_ + kvh) * S_ * HD_;
  const unsigned short* Vb = Vt + (size_t)(b * KVH_ + kvh) * HD_ * S_;

  for (int half = 0; half < 2; ++half) {
    const int qb = half ? (S_ / 64 - 1 - bx) : bx;

    const unsigned short* qbase =
        Qr + ((size_t)(b * H_ + h) * S_ + qb * 64 + wave * 16 + lr) * HD_;
    bf16x8 qf[4];
#pragma unroll
    for (int t = 0; t < 4; ++t) qf[t] = ld8(qbase + t * 32 + lk);

    f32x4 acc_o[8];
#pragma unroll
    for (int dt = 0; dt < 8; ++dt) acc_o[dt] = (f32x4){0.f, 0.f, 0.f, 0.f};
    float mrow[4], lrow[4];
#pragma unroll
    for (int r = 0; r < 4; ++r) { mrow[r] = -1e30f; lrow[r] = 0.f; }

    for (int kb = 0; kb <= qb; ++kb) {
      __syncthreads();
#pragma unroll
      for (int i = 0; i < 4; ++i) {
        const int db = i * 4096 + tid * 16;  // dest byte (linear) in 16KB tile
        {  // K: row = db>>8 (0..63), 256 B/row
          const int row  = db >> 8;
          const int colb = (db & 255) ^ ((row & 7) << 4);
          cp16(Kb + (size_t)(kb * 64 + row) * HD_ + (colb >> 1),
               (char*)Kld + i * 4096 + wave * 1024);
        }
        {  // V: row = db>>7 (0..127), 128 B/row
          const int row  = db >> 7;
          const int colb = (db & 127) ^ ((row & 7) << 4);
          cp16(Vb + (size_t)row * S_ + kb * 64 + (colb >> 1),
               (char*)Vld + i * 4096 + wave * 1024);
        }
      }
      __syncthreads();

      // S = Q K^T for this wave's 16 rows x 64 cols
      f32x4 accs[4];
#pragma unroll
      for (int kt = 0; kt < 4; ++kt) accs[kt] = (f32x4){0.f, 0.f, 0.f, 0.f};
#pragma unroll
      for (int t = 0; t < 4; ++t) {
#pragma unroll
        for (int kt = 0; kt < 4; ++kt) {
          const int krow = kt * 16 + lr;
          const int kbyte = ((krow << 8) + ((t * 32 + lk) << 1)) ^ ((krow & 7) << 4);
          bf16x8 kf = ld8b(Kld, kbyte);
          accs[kt] = __builtin_amdgcn_mfma_f32_16x16x32_bf16(qf[t], kf, accs[kt], 0, 0, 0);
        }
      }

      const bool last = (kb == qb);
      float sv[4][4];
#pragma unroll
      for (int r = 0; r < 4; ++r) {
        const int qg = qb * 64 + wave * 16 + orow + r;
#pragma unroll
        for (int kt = 0; kt < 4; ++kt) {
          float v = accs[kt][r] * scale;
          int kg = kb * 64 + kt * 16 + lr;
          if (last && kg > qg) v = -1e30f;
          sv[r][kt] = v;
        }
      }

      float mnew[4], corr[4];
#pragma unroll
      for (int r = 0; r < 4; ++r) {
        float mx = fmaxf(fmaxf(sv[r][0], sv[r][1]), fmaxf(sv[r][2], sv[r][3]));
#pragma unroll
        for (int msk = 8; msk >= 1; msk >>= 1) mx = fmaxf(mx, __shfl_xor(mx, msk, 64));
        mnew[r] = fmaxf(mrow[r], mx);
        corr[r] = __expf(mrow[r] - mnew[r]);
        mrow[r] = mnew[r];
      }
#pragma unroll
      for (int r = 0; r < 4; ++r) {
        float su = 0.f;
#pragma unroll
        for (int kt = 0; kt < 4; ++kt) {
          float p = __expf(sv[r][kt] - mnew[r]);
          su += p;
          const int prow = orow + r;
          const int pbyte = ((prow << 7) + ((kt * 16 + lr) << 1)) ^ ((prow & 7) << 4);
          *(unsigned short*)((char*)&Pld[wave][0] + pbyte) = f2bf(p);
        }
#pragma unroll
        for (int msk = 8; msk >= 1; msk >>= 1) su += __shfl_xor(su, msk, 64);
        lrow[r] = lrow[r] * corr[r] + su;
      }
#pragma unroll
      for (int dt = 0; dt < 8; ++dt)
#pragma unroll
        for (int r = 0; r < 4; ++r) acc_o[dt][r] *= corr[r];

      // Compiler fence: Pld written as ushort, read as bf16x8 below (TBAA).
      asm volatile("" ::: "memory");

      // O += P V   (P: [16q x 64k] swz, V: Vld[d][k] k-contig swz)
#pragma unroll
      for (int kc = 0; kc < 2; ++kc) {
        const int pbyte = ((lr << 7) + ((kc * 32 + lk) << 1)) ^ ((lr & 7) << 4);
        bf16x8 pf = ld8b(&Pld[wave][0], pbyte);
#pragma unroll
        for (int dt = 0; dt < 8; ++dt) {
          const int vrow = dt * 16 + lr;
          const int vbyte = ((vrow << 7) + ((kc * 32 + lk) << 1)) ^ ((vrow & 7) << 4);
          bf16x8 vf = ld8b(Vld, vbyte);
          acc_o[dt] = __builtin_amdgcn_mfma_f32_16x16x32_bf16(pf, vf, acc_o[dt], 0, 0, 0);
        }
      }
    }

#pragma unroll
    for (int r = 0; r < 4; ++r) {
      float inv = 1.f / lrow[r];
      size_t rowoff =
          (size_t)(b * S_ + qb * 64 + wave * 16 + orow + r) * (H_ * HD_) + h * HD_;
#pragma unroll
      for (int dt = 0; dt < 8; ++dt)
        O[rowoff + dt * 16 + lr] = f2bf(acc_o[dt][r] * inv);
    }
  }
}

// Diagnostic: if ws_size is too small, fill fp32 output with sentinel 12345.
__global__ void fill_sentinel(float* __restrict__ O, int n) {
  int i = blockIdx.x * 256 + threadIdx.x;
  if (i < n) O[i] = 12345.0f;
}

// ---------------------------------------------------------------------------
extern "C" void kernel_launch(void* const* d_in, const int* in_sizes, int n_in,
                              void* d_out, int out_size, void* d_ws, size_t ws_size,
                              hipStream_t stream) {
  const float* hidden = (const float*)d_in[0]; // [B,S,D] fp32
  const float* wqkv   = (const float*)d_in[1]; // [6144,4096] fp32
  const float* wdense = (const float*)d_in[2]; // [4096,4096] fp32
  float* out = (float*)d_out;                  // [B,S,4096] fp32

  const size_t NEED = 134217728;
  if (ws_size < NEED) {
    fill_sentinel<<<dim3((out_size + 255) / 256), dim3(256), 0, stream>>>(out, out_size);
    return;
  }

  char* ws = (char*)d_ws;
  // Phase 1 layout
  unsigned short* Hb    = (unsigned short*)(ws);                 // 33,554,432 B
  unsigned short* Wqb   = (unsigned short*)(ws + 33554432);      // 50,331,648 B
  unsigned short* fused = (unsigned short*)(ws + 83886080);      // 50,331,648 B
  // Phase 2 layout (after GEMM1: Hb/Wqb dead)
  unsigned short* Qr    = (unsigned short*)(ws);                 // 33,554,432 B
  unsigned short* Kr    = (unsigned short*)(ws + 33554432);      //  8,388,608 B
  unsigned short* Vt    = (unsigned short*)(ws + 41943040);      //  8,388,608 B
  unsigned short* Wdb   = (unsigned short*)(ws + 50331648);      // 33,554,432 B
  unsigned short* attn_out = (unsigned short*)(ws + 83886080);   // 33,554,432 B (over fused)

  const int nH = B_ * S_ * D_;      // 16,777,216
  const int nQ = NE_ * D_;          // 25,165,824
  const int nD = D_ * D_;           // 16,777,216

  cvt_f32_bf16<<<dim3(nH / 4 / 256), dim3(256), 0, stream>>>(hidden, Hb, nH / 4);
  cvt_f32_bf16<<<dim3(nQ / 4 / 256), dim3(256), 0, stream>>>(wqkv, Wqb, nQ / 4);

  gemm_bt<unsigned short><<<dim3(NE_ / 128, (B_ * S_) / 128), dim3(256), 0, stream>>>(
      Hb, Wqb, fused, B_ * S_, NE_, D_);

  cvt_f32_bf16<<<dim3(nD / 4 / 256), dim3(256), 0, stream>>>(wdense, Wdb, nD / 4);

  rope_scatter<<<dim3((B_ * S_ * 48 * 64) / 256), dim3(256), 0, stream>>>(
      fused, Qr, Kr, Vt);

  attn_fwd<<<dim3(16, H_, B_), dim3(256), 0, stream>>>(Qr, Kr, Vt, attn_out);

  gemm_bt<float><<<dim3(D_ / 128, (B_ * S_) / 128), dim3(256), 0, stream>>>(
      attn_out, Wdb, out, B_ * S_, D_, D_);
}

// Round 5
// 643.035 us; speedup vs baseline: 1.6913x; 1.1349x over previous
//
#include <hip/hip_runtime.h>

#define B_   2
#define S_   2048
#define D_   4096
#define H_   32
#define KVH_ 8
#define HD_  128
#define NE_  6144   // (KVH*2+H)*HD

using f32x4  = __attribute__((ext_vector_type(4))) float;
using bf16x8 = __attribute__((ext_vector_type(8))) __bf16;

__device__ __forceinline__ unsigned short f2bf(float f) {
  union { float f; unsigned u; } v; v.f = f;
  unsigned r = v.u + 0x7FFFu + ((v.u >> 16) & 1u);
  return (unsigned short)(r >> 16);
}
__device__ __forceinline__ float bf2f(unsigned short h) {
  union { unsigned u; float f; } v; v.u = ((unsigned)h) << 16; return v.f;
}
__device__ __forceinline__ bf16x8 ld8(const unsigned short* p) {
  return *reinterpret_cast<const bf16x8*>(p);
}
__device__ __forceinline__ bf16x8 ld8b(const void* base, int byte_off) {
  return *reinterpret_cast<const bf16x8*>((const char*)base + byte_off);
}
__device__ __forceinline__ void cp16(const void* g, void* l) {
  __builtin_amdgcn_global_load_lds(
      (const __attribute__((address_space(1))) void*)g,
      (__attribute__((address_space(3))) void*)l, 16, 0, 0);
}

// ---------------------------------------------------------------------------
// fp32 -> bf16 (RNE), 4 elems/thread.
// ---------------------------------------------------------------------------
__global__ __launch_bounds__(256) void cvt_f32_bf16(
    const float* __restrict__ in, unsigned short* __restrict__ out, int n4)
{
  int i = blockIdx.x * 256 + threadIdx.x;
  if (i >= n4) return;
  f32x4 v = *reinterpret_cast<const f32x4*>(in + (size_t)i * 4);
  ushort4 o;
  o.x = f2bf(v[0]); o.y = f2bf(v[1]); o.z = f2bf(v[2]); o.w = f2bf(v[3]);
  *reinterpret_cast<ushort4*>(out + (size_t)i * 4) = o;
}

// ---------------------------------------------------------------------------
// C[M,N] = A[M,K] * B[N,K]^T  (A,B bf16 bits; fp32 accum; OutT = ushort|float)
// 128x128 tile, BK=64, 4 waves (2x2), 16x16x32 bf16 MFMA.
// Double-buffered LDS (2x32KB), single barrier per K-iter, stage-before-
// compute (T3-min). LDS XOR-swizzle byte^=(row&7)<<4: linear gload_lds dest +
// inverse-swizzled GLOBAL source column + swizzled ds_read (rule #21).
// XCD-aware block swizzle (nwg%8==0 guarded).
// ---------------------------------------------------------------------------
template <typename OutT>
__global__ __launch_bounds__(256) void gemm_bt(
    const unsigned short* __restrict__ A,
    const unsigned short* __restrict__ Bw,
    OutT* __restrict__ C,
    int M, int N, int K)
{
  __shared__ __align__(16) unsigned short As[2][128 * 64];
  __shared__ __align__(16) unsigned short Bs[2][128 * 64];
  const int tid  = threadIdx.x;
  const int lane = tid & 63;
  const int wave = tid >> 6;
  const int wr = wave >> 1, wc = wave & 1;
  const int lr = lane & 15;
  const int lk = (lane >> 4) * 8;

  // XCD swizzle (m157): same-XCD blocks get contiguous logical tiles.
  int id  = blockIdx.y * gridDim.x + blockIdx.x;
  const int nwg = gridDim.x * gridDim.y;
  if ((nwg & 7) == 0) {
    const int q = nwg >> 3;
    id = (id & 7) * q + (id >> 3);
  }
  const int row0 = (id / gridDim.x) * 128;
  const int col0 = (id % gridDim.x) * 128;

  // Staging pointers: slot i covers dest bytes [i*4096 + tid*16, +16).
  // Physical dest is linear; source column is inverse-swizzled.
  const unsigned short* aS[4];
  const unsigned short* bS[4];
  char* aD[4];
  char* bD[4];
#pragma unroll
  for (int i = 0; i < 4; ++i) {
    const int db  = i * 4096 + tid * 16;           // physical byte in 16KB tile
    const int row = db >> 7;                       // 128 B per row
    const int col = ((db & 127) ^ ((row & 7) << 4)) >> 1;
    aS[i] = A  + (size_t)(row0 + row) * K + col;
    bS[i] = Bw + (size_t)(col0 + row) * K + col;
    aD[i] = (char*)(&As[0][0]) + db;
    bD[i] = (char*)(&Bs[0][0]) + db;
  }

  f32x4 acc[4][4];
#pragma unroll
  for (int m = 0; m < 4; ++m)
#pragma unroll
    for (int n = 0; n < 4; ++n) acc[m][n] = (f32x4){0.f, 0.f, 0.f, 0.f};

  auto stage = [&](int buf) {
#pragma unroll
    for (int i = 0; i < 4; ++i) {
      cp16(aS[i], aD[i] + buf * 16384);
      cp16(bS[i], bD[i] + buf * 16384);
      aS[i] += 64;
      bS[i] += 64;
    }
  };

  const int nt = K >> 6;
  stage(0);
  __syncthreads();   // compiler emits vmcnt(0) drain before barrier

  for (int t = 0; t < nt; ++t) {
    const int cur = t & 1;
    if (t + 1 < nt) stage(cur ^ 1);   // issue next-tile loads FIRST

    const unsigned short* Ab = &As[0][0] + cur * 8192;
    const unsigned short* Bb = &Bs[0][0] + cur * 8192;
#pragma unroll
    for (int kk = 0; kk < 2; ++kk) {
      const int cb = ((kk * 32 + lk) << 1) ^ ((lr & 7) << 4);  // swizzled col byte
      bf16x8 af[4], bfr[4];
#pragma unroll
      for (int m = 0; m < 4; ++m)
        af[m] = ld8b(Ab, (wr * 64 + m * 16 + lr) * 128 + cb);
#pragma unroll
      for (int n = 0; n < 4; ++n)
        bfr[n] = ld8b(Bb, (wc * 64 + n * 16 + lr) * 128 + cb);
#pragma unroll
      for (int m = 0; m < 4; ++m)
#pragma unroll
        for (int n = 0; n < 4; ++n)
          acc[m][n] = __builtin_amdgcn_mfma_f32_16x16x32_bf16(af[m], bfr[n], acc[m][n], 0, 0, 0);
    }
    __syncthreads();  // drains vmcnt (next-tile loads landed) + gates overwrite
  }

  const int orow = (lane >> 4) * 4;
#pragma unroll
  for (int m = 0; m < 4; ++m) {
    const int gr0 = row0 + wr * 64 + m * 16 + orow;
#pragma unroll
    for (int n = 0; n < 4; ++n) {
      const int gc = col0 + wc * 64 + n * 16 + lr;
#pragma unroll
      for (int r = 0; r < 4; ++r) {
        float val = acc[m][n][r];
        if constexpr (sizeof(OutT) == 2)
          C[(size_t)(gr0 + r) * N + gc] = f2bf(val);
        else
          C[(size_t)(gr0 + r) * N + gc] = val;
      }
    }
  }
}

// ---------------------------------------------------------------------------
// Split fused[B,S,48,128] (per kv-group: q0 q1 q2 q3 k v) into
//   Qr[B,H,S,128] (rope), Kr[B,KVH,S,128] (rope), Vt[B,KVH,128,S] (transposed)
// ---------------------------------------------------------------------------
__global__ __launch_bounds__(256) void rope_scatter(
    const unsigned short* __restrict__ fused,
    unsigned short* __restrict__ Qr,
    unsigned short* __restrict__ Kr,
    unsigned short* __restrict__ Vt)
{
  int idx = blockIdx.x * 256 + threadIdx.x;  // [0, B*S*48*64)
  int d = idx & 63;
  int t = idx >> 6;
  int e = t % 48;
  int bs = t / 48;
  int s = bs % S_;
  int b = bs / S_;
  int kvh = e / 6, j = e % 6;
  const unsigned short* src = fused + (size_t)bs * NE_ + e * 128;
  unsigned short u1 = src[d];
  unsigned short u2 = src[d + 64];
  if (j == 5) {  // V: transposed store
    size_t base = (size_t)(b * KVH_ + kvh) * HD_ * S_;
    Vt[base + (size_t)d * S_ + s]        = u1;
    Vt[base + (size_t)(d + 64) * S_ + s] = u2;
  } else {
    float x1 = bf2f(u1), x2 = bf2f(u2);
    float inv = __expf(-(float)d * (9.2103403719761836f / 64.0f)); // 10000^(-d/64)
    float ang = (float)s * inv;
    float sn, c;
    sincosf(ang, &sn, &c);
    float o1 = x1 * c - x2 * sn;
    float o2 = x2 * c + x1 * sn;
    unsigned short* dst;
    if (j == 4) dst = Kr + ((size_t)(b * KVH_ + kvh) * S_ + s) * HD_;
    else        dst = Qr + ((size_t)(b * H_ + kvh * 4 + j) * S_ + s) * HD_;
    dst[d]      = f2bf(o1);
    dst[d + 64] = f2bf(o2);
  }
}

// ---------------------------------------------------------------------------
// Causal GQA flash attention, bank-conflict-free via XOR swizzle, load-balanced.
// Block = (bx, h, b): handles q-tiles qb=bx and qb=31-bx (33 KV-iters each).
// ---------------------------------------------------------------------------
__global__ __launch_bounds__(256) void attn_fwd(
    const unsigned short* __restrict__ Qr,
    const unsigned short* __restrict__ Kr,
    const unsigned short* __restrict__ Vt,
    unsigned short* __restrict__ O)
{
  __shared__ __align__(16) unsigned short Kld[64 * 128];
  __shared__ __align__(16) unsigned short Vld[128 * 64];
  __shared__ __align__(16) unsigned short Pld[4][16 * 64];

  const int tid  = threadIdx.x;
  const int lane = tid & 63;
  const int wave = tid >> 6;
  const int bx = blockIdx.x;   // 0..15
  const int h  = blockIdx.y;   // 0..31
  const int b  = blockIdx.z;   // 0..1
  const int kvh = h >> 2;
  const int lr = lane & 15;
  const int lk = (lane >> 4) * 8;
  const int orow = (lane >> 4) * 4;

  const float scale = 0.08838834764831845f;  // 1/sqrt(128)
  const unsigned short* Kb = Kr + (size_t)(b * KVH_ + kvh) * S_ * HD_;
  const unsigned short* Vb = Vt + (size_t)(b * KVH_ + kvh) * HD_ * S_;

  for (int half = 0; half < 2; ++half) {
    const int qb = half ? (S_ / 64 - 1 - bx) : bx;

    const unsigned short* qbase =
        Qr + ((size_t)(b * H_ + h) * S_ + qb * 64 + wave * 16 + lr) * HD_;
    bf16x8 qf[4];
#pragma unroll
    for (int t = 0; t < 4; ++t) qf[t] = ld8(qbase + t * 32 + lk);

    f32x4 acc_o[8];
#pragma unroll
    for (int dt = 0; dt < 8; ++dt) acc_o[dt] = (f32x4){0.f, 0.f, 0.f, 0.f};
    float mrow[4], lrow[4];
#pragma unroll
    for (int r = 0; r < 4; ++r) { mrow[r] = -1e30f; lrow[r] = 0.f; }

    for (int kb = 0; kb <= qb; ++kb) {
      __syncthreads();
#pragma unroll
      for (int i = 0; i < 4; ++i) {
        const int db = i * 4096 + tid * 16;  // dest byte (linear) in 16KB tile
        {  // K: row = db>>8 (0..63), 256 B/row
          const int row  = db >> 8;
          const int colb = (db & 255) ^ ((row & 7) << 4);
          cp16(Kb + (size_t)(kb * 64 + row) * HD_ + (colb >> 1),
               (char*)Kld + i * 4096 + wave * 1024);
        }
        {  // V: row = db>>7 (0..127), 128 B/row
          const int row  = db >> 7;
          const int colb = (db & 127) ^ ((row & 7) << 4);
          cp16(Vb + (size_t)row * S_ + kb * 64 + (colb >> 1),
               (char*)Vld + i * 4096 + wave * 1024);
        }
      }
      __syncthreads();

      // S = Q K^T for this wave's 16 rows x 64 cols
      f32x4 accs[4];
#pragma unroll
      for (int kt = 0; kt < 4; ++kt) accs[kt] = (f32x4){0.f, 0.f, 0.f, 0.f};
#pragma unroll
      for (int t = 0; t < 4; ++t) {
#pragma unroll
        for (int kt = 0; kt < 4; ++kt) {
          const int krow = kt * 16 + lr;
          const int kbyte = ((krow << 8) + ((t * 32 + lk) << 1)) ^ ((krow & 7) << 4);
          bf16x8 kf = ld8b(Kld, kbyte);
          accs[kt] = __builtin_amdgcn_mfma_f32_16x16x32_bf16(qf[t], kf, accs[kt], 0, 0, 0);
        }
      }

      const bool last = (kb == qb);
      float sv[4][4];
#pragma unroll
      for (int r = 0; r < 4; ++r) {
        const int qg = qb * 64 + wave * 16 + orow + r;
#pragma unroll
        for (int kt = 0; kt < 4; ++kt) {
          float v = accs[kt][r] * scale;
          int kg = kb * 64 + kt * 16 + lr;
          if (last && kg > qg) v = -1e30f;
          sv[r][kt] = v;
        }
      }

      float mnew[4], corr[4];
#pragma unroll
      for (int r = 0; r < 4; ++r) {
        float mx = fmaxf(fmaxf(sv[r][0], sv[r][1]), fmaxf(sv[r][2], sv[r][3]));
#pragma unroll
        for (int msk = 8; msk >= 1; msk >>= 1) mx = fmaxf(mx, __shfl_xor(mx, msk, 64));
        mnew[r] = fmaxf(mrow[r], mx);
        corr[r] = __expf(mrow[r] - mnew[r]);
        mrow[r] = mnew[r];
      }
#pragma unroll
      for (int r = 0; r < 4; ++r) {
        float su = 0.f;
#pragma unroll
        for (int kt = 0; kt < 4; ++kt) {
          float p = __expf(sv[r][kt] - mnew[r]);
          su += p;
          const int prow = orow + r;
          const int pbyte = ((prow << 7) + ((kt * 16 + lr) << 1)) ^ ((prow & 7) << 4);
          *(unsigned short*)((char*)&Pld[wave][0] + pbyte) = f2bf(p);
        }
#pragma unroll
        for (int msk = 8; msk >= 1; msk >>= 1) su += __shfl_xor(su, msk, 64);
        lrow[r] = lrow[r] * corr[r] + su;
      }
#pragma unroll
      for (int dt = 0; dt < 8; ++dt)
#pragma unroll
        for (int r = 0; r < 4; ++r) acc_o[dt][r] *= corr[r];

      // Compiler fence: Pld written as ushort, read as bf16x8 below (TBAA).
      asm volatile("" ::: "memory");

      // O += P V   (P: [16q x 64k] swz, V: Vld[d][k] k-contig swz)
#pragma unroll
      for (int kc = 0; kc < 2; ++kc) {
        const int pbyte = ((lr << 7) + ((kc * 32 + lk) << 1)) ^ ((lr & 7) << 4);
        bf16x8 pf = ld8b(&Pld[wave][0], pbyte);
#pragma unroll
        for (int dt = 0; dt < 8; ++dt) {
          const int vrow = dt * 16 + lr;
          const int vbyte = ((vrow << 7) + ((kc * 32 + lk) << 1)) ^ ((vrow & 7) << 4);
          bf16x8 vf = ld8b(Vld, vbyte);
          acc_o[dt] = __builtin_amdgcn_mfma_f32_16x16x32_bf16(pf, vf, acc_o[dt], 0, 0, 0);
        }
      }
    }

#pragma unroll
    for (int r = 0; r < 4; ++r) {
      float inv = 1.f / lrow[r];
      size_t rowoff =
          (size_t)(b * S_ + qb * 64 + wave * 16 + orow + r) * (H_ * HD_) + h * HD_;
#pragma unroll
      for (int dt = 0; dt < 8; ++dt)
        O[rowoff + dt * 16 + lr] = f2bf(acc_o[dt][r] * inv);
    }
  }
}

// Diagnostic: if ws_size is too small, fill fp32 output with sentinel 12345.
__global__ void fill_sentinel(float* __restrict__ O, int n) {
  int i = blockIdx.x * 256 + threadIdx.x;
  if (i < n) O[i] = 12345.0f;
}

// ---------------------------------------------------------------------------
extern "C" void kernel_launch(void* const* d_in, const int* in_sizes, int n_in,
                              void* d_out, int out_size, void* d_ws, size_t ws_size,
                              hipStream_t stream) {
  const float* hidden = (const float*)d_in[0]; // [B,S,D] fp32
  const float* wqkv   = (const float*)d_in[1]; // [6144,4096] fp32
  const float* wdense = (const float*)d_in[2]; // [4096,4096] fp32
  float* out = (float*)d_out;                  // [B,S,4096] fp32

  const size_t NEED = 134217728;
  if (ws_size < NEED) {
    fill_sentinel<<<dim3((out_size + 255) / 256), dim3(256), 0, stream>>>(out, out_size);
    return;
  }

  char* ws = (char*)d_ws;
  // Phase 1 layout
  unsigned short* Hb    = (unsigned short*)(ws);                 // 33,554,432 B
  unsigned short* Wqb   = (unsigned short*)(ws + 33554432);      // 50,331,648 B
  unsigned short* fused = (unsigned short*)(ws + 83886080);      // 50,331,648 B
  // Phase 2 layout (after GEMM1: Hb/Wqb dead)
  unsigned short* Qr    = (unsigned short*)(ws);                 // 33,554,432 B
  unsigned short* Kr    = (unsigned short*)(ws + 33554432);      //  8,388,608 B
  unsigned short* Vt    = (unsigned short*)(ws + 41943040);      //  8,388,608 B
  unsigned short* Wdb   = (unsigned short*)(ws + 50331648);      // 33,554,432 B
  unsigned short* attn_out = (unsigned short*)(ws + 83886080);   // 33,554,432 B (over fused)

  const int nH = B_ * S_ * D_;      // 16,777,216
  const int nQ = NE_ * D_;          // 25,165,824
  const int nD = D_ * D_;           // 16,777,216

  cvt_f32_bf16<<<dim3(nH / 4 / 256), dim3(256), 0, stream>>>(hidden, Hb, nH / 4);
  cvt_f32_bf16<<<dim3(nQ / 4 / 256), dim3(256), 0, stream>>>(wqkv, Wqb, nQ / 4);

  gemm_bt<unsigned short><<<dim3(NE_ / 128, (B_ * S_) / 128), dim3(256), 0, stream>>>(
      Hb, Wqb, fused, B_ * S_, NE_, D_);

  cvt_f32_bf16<<<dim3(nD / 4 / 256), dim3(256), 0, stream>>>(wdense, Wdb, nD / 4);

  rope_scatter<<<dim3((B_ * S_ * 48 * 64) / 256), dim3(256), 0, stream>>>(
      fused, Qr, Kr, Vt);

  attn_fwd<<<dim3(16, H_, B_), dim3(256), 0, stream>>>(Qr, Kr, Vt, attn_out);

  gemm_bt<float><<<dim3(D_ / 128, (B_ * S_) / 128), dim3(256), 0, stream>>>(
      attn_out, Wdb, out, B_ * S_, D_, D_);
}

// Round 6
// 575.628 us; speedup vs baseline: 1.8893x; 1.1171x over previous
//
#include <hip/hip_runtime.h>

#define B_   2
#define S_   2048
#define D_   4096
#define H_   32
#define KVH_ 8
#define HD_  128
#define NE_  6144   // (KVH*2+H)*HD

using f32x4  = __attribute__((ext_vector_type(4))) float;
using bf16x8 = __attribute__((ext_vector_type(8))) __bf16;

__device__ __forceinline__ unsigned short f2bf(float f) {
  union { float f; unsigned u; } v; v.f = f;
  unsigned r = v.u + 0x7FFFu + ((v.u >> 16) & 1u);
  return (unsigned short)(r >> 16);
}
__device__ __forceinline__ float bf2f(unsigned short h) {
  union { unsigned u; float f; } v; v.u = ((unsigned)h) << 16; return v.f;
}
__device__ __forceinline__ bf16x8 ld8(const unsigned short* p) {
  return *reinterpret_cast<const bf16x8*>(p);
}
__device__ __forceinline__ bf16x8 ld8b(const void* base, int byte_off) {
  return *reinterpret_cast<const bf16x8*>((const char*)base + byte_off);
}
__device__ __forceinline__ void cp16(const void* g, void* l) {
  __builtin_amdgcn_global_load_lds(
      (const __attribute__((address_space(1))) void*)g,
      (__attribute__((address_space(3))) void*)l, 16, 0, 0);
}

// ---------------------------------------------------------------------------
// fp32 -> bf16 (RNE), 4 elems/thread.
// ---------------------------------------------------------------------------
__global__ __launch_bounds__(256) void cvt_f32_bf16(
    const float* __restrict__ in, unsigned short* __restrict__ out, int n4)
{
  int i = blockIdx.x * 256 + threadIdx.x;
  if (i >= n4) return;
  f32x4 v = *reinterpret_cast<const f32x4*>(in + (size_t)i * 4);
  ushort4 o;
  o.x = f2bf(v[0]); o.y = f2bf(v[1]); o.z = f2bf(v[2]); o.w = f2bf(v[3]);
  *reinterpret_cast<ushort4*>(out + (size_t)i * 4) = o;
}

// ---------------------------------------------------------------------------
// 256x256-tile 8-phase GEMM: C[M,N] = A[M,K] * B[N,K]^T, K=4096 fixed.
// 8 waves (2M x 4N), per-wave C = 128x64. BK=64, 2 K-tiles/iteration,
// 8 phases each {ds_read subtile; stage 1 half-tile; s_barrier;
// setprio(1); 16 MFMA; setprio(0); [vmcnt@P4/P8]; s_barrier}.
// LDS 128 KiB: A[2buf][256][64], B[2buf][256][64], XOR-swizzle
// byte^=(row&7)<<4 via inverse-swizzled global source (rule #21).
// Counted vmcnt(4): each wave's vmcnt+barrier proves all waves' older
// stages landed before the region is read. Last iter: vmcnt(0).
// ---------------------------------------------------------------------------
template <typename OutT>
__global__ __launch_bounds__(512, 2) void gemm256(
    const unsigned short* __restrict__ A,
    const unsigned short* __restrict__ Bw,
    OutT* __restrict__ C, int M, int N)
{
  constexpr int K  = 4096;
  constexpr int NI = (K / 64) / 2;   // 32 iterations, 2 K-tiles each
  __shared__ __align__(16) char lds[131072];

  const int tid  = threadIdx.x;
  const int lane = tid & 63;
  const int wave = tid >> 6;
  const int wr = wave >> 2;          // 0..1  (M half)
  const int wc = wave & 3;           // 0..3  (N quarter)
  const int lr = lane & 15;
  const int lk = (lane >> 4) * 8;

  // XCD-aware swizzle (nwg % 8 == 0 for both call sites).
  int id  = blockIdx.y * gridDim.x + blockIdx.x;
  const int nwg = gridDim.x * gridDim.y;
  if ((nwg & 7) == 0) { const int q = nwg >> 3; id = (id & 7) * q + (id >> 3); }
  const int row0 = (id / gridDim.x) * 256;
  const int col0 = (id % gridDim.x) * 256;

  // Staging geometry: half-tile = 128 rows x 64 cols = 16 KB = 2 loads/thread.
  int rw[2], cs[2], db[2];
#pragma unroll
  for (int j = 0; j < 2; ++j) {
    db[j] = j * 8192 + tid * 16;                     // linear dest byte
    rw[j] = db[j] >> 7;                              // row within half
    cs[j] = ((db[j] & 127) ^ ((rw[j] & 7) << 4)) >> 1;  // inv-swizzled src col
  }

  auto stA = [&](int buf, int h, int t) {
#pragma unroll
    for (int j = 0; j < 2; ++j)
      cp16(A + (size_t)(row0 + h * 128 + rw[j]) * K + t * 64 + cs[j],
           lds + buf * 32768 + h * 16384 + db[j]);
  };
  auto stB = [&](int buf, int h, int t) {
#pragma unroll
    for (int j = 0; j < 2; ++j)
      cp16(Bw + (size_t)(col0 + h * 128 + rw[j]) * K + t * 64 + cs[j],
           lds + 65536 + buf * 32768 + h * 16384 + db[j]);
  };

  const int cb0 = ((0 + lk) << 1) ^ ((lr & 7) << 4);   // kk=0 swizzled col byte
  const int cb1 = ((32 + lk) << 1) ^ ((lr & 7) << 4);  // kk=1
  const int aRowB = (wr * 128 + lr) * 128;             // A row byte base (m=0)
  const int bRowB = (wc * 64 + lr) * 128;              // B row byte base (n=0)

  f32x4 acc[8][4];
#pragma unroll
  for (int m = 0; m < 8; ++m)
#pragma unroll
    for (int n = 0; n < 4; ++n) acc[m][n] = (f32x4){0.f, 0.f, 0.f, 0.f};
  bf16x8 bfr[4][2];

#define FENCE asm volatile("" ::: "memory")
#define VM4   asm volatile("s_waitcnt vmcnt(4)" ::: "memory")
#define VM0   asm volatile("s_waitcnt vmcnt(0)" ::: "memory")

#define PHASE(p, buf, STAGE, WAIT)                                             \
  {                                                                            \
    if ((p) == 0) {                                                            \
      _Pragma("unroll")                                                        \
      for (int n = 0; n < 4; ++n) {                                            \
        bfr[n][0] = ld8b(lds, 65536 + (buf) * 32768 + bRowB + n * 2048 + cb0); \
        bfr[n][1] = ld8b(lds, 65536 + (buf) * 32768 + bRowB + n * 2048 + cb1); \
      }                                                                        \
    }                                                                          \
    bf16x8 a00 = ld8b(lds, (buf) * 32768 + aRowB + ((p) * 2 + 0) * 2048 + cb0);\
    bf16x8 a01 = ld8b(lds, (buf) * 32768 + aRowB + ((p) * 2 + 0) * 2048 + cb1);\
    bf16x8 a10 = ld8b(lds, (buf) * 32768 + aRowB + ((p) * 2 + 1) * 2048 + cb0);\
    bf16x8 a11 = ld8b(lds, (buf) * 32768 + aRowB + ((p) * 2 + 1) * 2048 + cb1);\
    STAGE;                                                                     \
    FENCE;                                                                     \
    __builtin_amdgcn_s_barrier();                                              \
    __builtin_amdgcn_s_setprio(1);                                             \
    _Pragma("unroll")                                                          \
    for (int n = 0; n < 4; ++n) {                                              \
      acc[(p)*2+0][n] = __builtin_amdgcn_mfma_f32_16x16x32_bf16(a00, bfr[n][0], acc[(p)*2+0][n], 0, 0, 0); \
      acc[(p)*2+0][n] = __builtin_amdgcn_mfma_f32_16x16x32_bf16(a01, bfr[n][1], acc[(p)*2+0][n], 0, 0, 0); \
      acc[(p)*2+1][n] = __builtin_amdgcn_mfma_f32_16x16x32_bf16(a10, bfr[n][0], acc[(p)*2+1][n], 0, 0, 0); \
      acc[(p)*2+1][n] = __builtin_amdgcn_mfma_f32_16x16x32_bf16(a11, bfr[n][1], acc[(p)*2+1][n], 0, 0, 0); \
    }                                                                          \
    __builtin_amdgcn_s_setprio(0);                                             \
    WAIT;                                                                      \
    FENCE;                                                                     \
    __builtin_amdgcn_s_barrier();                                              \
  }

  // Prologue: tile0 A+B into buf0, tile1 B into buf1 (12 loads/wave).
  stB(0, 0, 0); stB(0, 1, 0); stA(0, 0, 0); stA(0, 1, 0);
  stB(1, 0, 1); stB(1, 1, 1);
  VM4;   // tile0 fully landed; tile1-B may remain in flight
  FENCE;
  __builtin_amdgcn_s_barrier();

  for (int i = 0; i < NI; ++i) {
    const int t1  = 2 * i + 1;
    const int tn0 = 2 * i + 2;
    const int tn1 = 2 * i + 3;
    const bool pre = (i + 1 < NI);
    // K-tile 2i in buf0
    PHASE(0, 0, { stA(1, 0, t1); }, {});
    PHASE(1, 0, { stA(1, 1, t1); }, {});
    PHASE(2, 0, { if (pre) stB(0, 0, tn0); }, {});
    PHASE(3, 0, { if (pre) stB(0, 1, tn0); },
          { if (pre) { VM4; } else { VM0; } });
    // K-tile 2i+1 in buf1
    PHASE(0, 1, { if (pre) stA(0, 0, tn0); }, {});
    PHASE(1, 1, { if (pre) stA(0, 1, tn0); }, {});
    PHASE(2, 1, { if (pre) stB(1, 0, tn1); }, {});
    PHASE(3, 1, { if (pre) stB(1, 1, tn1); },
          { if (pre) { VM4; } });
  }
#undef PHASE
#undef FENCE
#undef VM4
#undef VM0

  const int orow = (lane >> 4) * 4;
#pragma unroll
  for (int m = 0; m < 8; ++m) {
    const int gr0 = row0 + wr * 128 + m * 16 + orow;
#pragma unroll
    for (int n = 0; n < 4; ++n) {
      const int gc = col0 + wc * 64 + n * 16 + lr;
#pragma unroll
      for (int r = 0; r < 4; ++r) {
        float val = acc[m][n][r];
        if constexpr (sizeof(OutT) == 2)
          C[(size_t)(gr0 + r) * N + gc] = f2bf(val);
        else
          C[(size_t)(gr0 + r) * N + gc] = val;
      }
    }
  }
}

// ---------------------------------------------------------------------------
// Split fused[B,S,48,128] (per kv-group: q0 q1 q2 q3 k v) into
//   Qr[B,H,S,128] (rope), Kr[B,KVH,S,128] (rope), Vt[B,KVH,128,S] (transposed)
// ---------------------------------------------------------------------------
__global__ __launch_bounds__(256) void rope_scatter(
    const unsigned short* __restrict__ fused,
    unsigned short* __restrict__ Qr,
    unsigned short* __restrict__ Kr,
    unsigned short* __restrict__ Vt)
{
  int idx = blockIdx.x * 256 + threadIdx.x;  // [0, B*S*48*64)
  int d = idx & 63;
  int t = idx >> 6;
  int e = t % 48;
  int bs = t / 48;
  int s = bs % S_;
  int b = bs / S_;
  int kvh = e / 6, j = e % 6;
  const unsigned short* src = fused + (size_t)bs * NE_ + e * 128;
  unsigned short u1 = src[d];
  unsigned short u2 = src[d + 64];
  if (j == 5) {  // V: transposed store
    size_t base = (size_t)(b * KVH_ + kvh) * HD_ * S_;
    Vt[base + (size_t)d * S_ + s]        = u1;
    Vt[base + (size_t)(d + 64) * S_ + s] = u2;
  } else {
    float x1 = bf2f(u1), x2 = bf2f(u2);
    float inv = __expf(-(float)d * (9.2103403719761836f / 64.0f)); // 10000^(-d/64)
    float ang = (float)s * inv;
    float sn, c;
    sincosf(ang, &sn, &c);
    float o1 = x1 * c - x2 * sn;
    float o2 = x2 * c + x1 * sn;
    unsigned short* dst;
    if (j == 4) dst = Kr + ((size_t)(b * KVH_ + kvh) * S_ + s) * HD_;
    else        dst = Qr + ((size_t)(b * H_ + kvh * 4 + j) * S_ + s) * HD_;
    dst[d]      = f2bf(o1);
    dst[d + 64] = f2bf(o2);
  }
}

// ---------------------------------------------------------------------------
// Causal GQA flash attention, bank-conflict-free via XOR swizzle, load-balanced.
// Block = (bx, h, b): handles q-tiles qb=bx and qb=31-bx (33 KV-iters each).
// ---------------------------------------------------------------------------
__global__ __launch_bounds__(256) void attn_fwd(
    const unsigned short* __restrict__ Qr,
    const unsigned short* __restrict__ Kr,
    const unsigned short* __restrict__ Vt,
    unsigned short* __restrict__ O)
{
  __shared__ __align__(16) unsigned short Kld[64 * 128];
  __shared__ __align__(16) unsigned short Vld[128 * 64];
  __shared__ __align__(16) unsigned short Pld[4][16 * 64];

  const int tid  = threadIdx.x;
  const int lane = tid & 63;
  const int wave = tid >> 6;
  const int bx = blockIdx.x;   // 0..15
  const int h  = blockIdx.y;   // 0..31
  const int b  = blockIdx.z;   // 0..1
  const int kvh = h >> 2;
  const int lr = lane & 15;
  const int lk = (lane >> 4) * 8;
  const int orow = (lane >> 4) * 4;

  const float scale = 0.08838834764831845f;  // 1/sqrt(128)
  const unsigned short* Kb = Kr + (size_t)(b * KVH_ + kvh) * S_ * HD_;
  const unsigned short* Vb = Vt + (size_t)(b * KVH_ + kvh) * HD_ * S_;

  for (int half = 0; half < 2; ++half) {
    const int qb = half ? (S_ / 64 - 1 - bx) : bx;

    const unsigned short* qbase =
        Qr + ((size_t)(b * H_ + h) * S_ + qb * 64 + wave * 16 + lr) * HD_;
    bf16x8 qf[4];
#pragma unroll
    for (int t = 0; t < 4; ++t) qf[t] = ld8(qbase + t * 32 + lk);

    f32x4 acc_o[8];
#pragma unroll
    for (int dt = 0; dt < 8; ++dt) acc_o[dt] = (f32x4){0.f, 0.f, 0.f, 0.f};
    float mrow[4], lrow[4];
#pragma unroll
    for (int r = 0; r < 4; ++r) { mrow[r] = -1e30f; lrow[r] = 0.f; }

    for (int kb = 0; kb <= qb; ++kb) {
      __syncthreads();
#pragma unroll
      for (int i = 0; i < 4; ++i) {
        const int db = i * 4096 + tid * 16;  // dest byte (linear) in 16KB tile
        {  // K: row = db>>8 (0..63), 256 B/row
          const int row  = db >> 8;
          const int colb = (db & 255) ^ ((row & 7) << 4);
          cp16(Kb + (size_t)(kb * 64 + row) * HD_ + (colb >> 1),
               (char*)Kld + i * 4096 + wave * 1024);
        }
        {  // V: row = db>>7 (0..127), 128 B/row
          const int row  = db >> 7;
          const int colb = (db & 127) ^ ((row & 7) << 4);
          cp16(Vb + (size_t)row * S_ + kb * 64 + (colb >> 1),
               (char*)Vld + i * 4096 + wave * 1024);
        }
      }
      __syncthreads();

      // S = Q K^T for this wave's 16 rows x 64 cols
      f32x4 accs[4];
#pragma unroll
      for (int kt = 0; kt < 4; ++kt) accs[kt] = (f32x4){0.f, 0.f, 0.f, 0.f};
#pragma unroll
      for (int t = 0; t < 4; ++t) {
#pragma unroll
        for (int kt = 0; kt < 4; ++kt) {
          const int krow = kt * 16 + lr;
          const int kbyte = ((krow << 8) + ((t * 32 + lk) << 1)) ^ ((krow & 7) << 4);
          bf16x8 kf = ld8b(Kld, kbyte);
          accs[kt] = __builtin_amdgcn_mfma_f32_16x16x32_bf16(qf[t], kf, accs[kt], 0, 0, 0);
        }
      }

      const bool last = (kb == qb);
      float sv[4][4];
#pragma unroll
      for (int r = 0; r < 4; ++r) {
        const int qg = qb * 64 + wave * 16 + orow + r;
#pragma unroll
        for (int kt = 0; kt < 4; ++kt) {
          float v = accs[kt][r] * scale;
          int kg = kb * 64 + kt * 16 + lr;
          if (last && kg > qg) v = -1e30f;
          sv[r][kt] = v;
        }
      }

      float mnew[4], corr[4];
#pragma unroll
      for (int r = 0; r < 4; ++r) {
        float mx = fmaxf(fmaxf(sv[r][0], sv[r][1]), fmaxf(sv[r][2], sv[r][3]));
#pragma unroll
        for (int msk = 8; msk >= 1; msk >>= 1) mx = fmaxf(mx, __shfl_xor(mx, msk, 64));
        mnew[r] = fmaxf(mrow[r], mx);
        corr[r] = __expf(mrow[r] - mnew[r]);
        mrow[r] = mnew[r];
      }
#pragma unroll
      for (int r = 0; r < 4; ++r) {
        float su = 0.f;
#pragma unroll
        for (int kt = 0; kt < 4; ++kt) {
          float p = __expf(sv[r][kt] - mnew[r]);
          su += p;
          const int prow = orow + r;
          const int pbyte = ((prow << 7) + ((kt * 16 + lr) << 1)) ^ ((prow & 7) << 4);
          *(unsigned short*)((char*)&Pld[wave][0] + pbyte) = f2bf(p);
        }
#pragma unroll
        for (int msk = 8; msk >= 1; msk >>= 1) su += __shfl_xor(su, msk, 64);
        lrow[r] = lrow[r] * corr[r] + su;
      }
#pragma unroll
      for (int dt = 0; dt < 8; ++dt)
#pragma unroll
        for (int r = 0; r < 4; ++r) acc_o[dt][r] *= corr[r];

      // Compiler fence: Pld written as ushort, read as bf16x8 below (TBAA).
      asm volatile("" ::: "memory");

      // O += P V   (P: [16q x 64k] swz, V: Vld[d][k] k-contig swz)
#pragma unroll
      for (int kc = 0; kc < 2; ++kc) {
        const int pbyte = ((lr << 7) + ((kc * 32 + lk) << 1)) ^ ((lr & 7) << 4);
        bf16x8 pf = ld8b(&Pld[wave][0], pbyte);
#pragma unroll
        for (int dt = 0; dt < 8; ++dt) {
          const int vrow = dt * 16 + lr;
          const int vbyte = ((vrow << 7) + ((kc * 32 + lk) << 1)) ^ ((vrow & 7) << 4);
          bf16x8 vf = ld8b(Vld, vbyte);
          acc_o[dt] = __builtin_amdgcn_mfma_f32_16x16x32_bf16(pf, vf, acc_o[dt], 0, 0, 0);
        }
      }
    }

#pragma unroll
    for (int r = 0; r < 4; ++r) {
      float inv = 1.f / lrow[r];
      size_t rowoff =
          (size_t)(b * S_ + qb * 64 + wave * 16 + orow + r) * (H_ * HD_) + h * HD_;
#pragma unroll
      for (int dt = 0; dt < 8; ++dt)
        O[rowoff + dt * 16 + lr] = f2bf(acc_o[dt][r] * inv);
    }
  }
}

// Diagnostic: if ws_size is too small, fill fp32 output with sentinel 12345.
__global__ void fill_sentinel(float* __restrict__ O, int n) {
  int i = blockIdx.x * 256 + threadIdx.x;
  if (i < n) O[i] = 12345.0f;
}

// ---------------------------------------------------------------------------
extern "C" void kernel_launch(void* const* d_in, const int* in_sizes, int n_in,
                              void* d_out, int out_size, void* d_ws, size_t ws_size,
                              hipStream_t stream) {
  const float* hidden = (const float*)d_in[0]; // [B,S,D] fp32
  const float* wqkv   = (const float*)d_in[1]; // [6144,4096] fp32
  const float* wdense = (const float*)d_in[2]; // [4096,4096] fp32
  float* out = (float*)d_out;                  // [B,S,4096] fp32

  const size_t NEED = 134217728;
  if (ws_size < NEED) {
    fill_sentinel<<<dim3((out_size + 255) / 256), dim3(256), 0, stream>>>(out, out_size);
    return;
  }

  char* ws = (char*)d_ws;
  // Phase 1 layout
  unsigned short* Hb    = (unsigned short*)(ws);                 // 33,554,432 B
  unsigned short* Wqb   = (unsigned short*)(ws + 33554432);      // 50,331,648 B
  unsigned short* fused = (unsigned short*)(ws + 83886080);      // 50,331,648 B
  // Phase 2 layout (after GEMM1: Hb/Wqb dead)
  unsigned short* Qr    = (unsigned short*)(ws);                 // 33,554,432 B
  unsigned short* Kr    = (unsigned short*)(ws + 33554432);      //  8,388,608 B
  unsigned short* Vt    = (unsigned short*)(ws + 41943040);      //  8,388,608 B
  unsigned short* Wdb   = (unsigned short*)(ws + 50331648);      // 33,554,432 B
  unsigned short* attn_out = (unsigned short*)(ws + 83886080);   // 33,554,432 B (over fused)

  const int nH = B_ * S_ * D_;      // 16,777,216
  const int nQ = NE_ * D_;          // 25,165,824
  const int nD = D_ * D_;           // 16,777,216

  cvt_f32_bf16<<<dim3(nH / 4 / 256), dim3(256), 0, stream>>>(hidden, Hb, nH / 4);
  cvt_f32_bf16<<<dim3(nQ / 4 / 256), dim3(256), 0, stream>>>(wqkv, Wqb, nQ / 4);

  gemm256<unsigned short><<<dim3(NE_ / 256, (B_ * S_) / 256), dim3(512), 0, stream>>>(
      Hb, Wqb, fused, B_ * S_, NE_);

  cvt_f32_bf16<<<dim3(nD / 4 / 256), dim3(256), 0, stream>>>(wdense, Wdb, nD / 4);

  rope_scatter<<<dim3((B_ * S_ * 48 * 64) / 256), dim3(256), 0, stream>>>(
      fused, Qr, Kr, Vt);

  attn_fwd<<<dim3(16, H_, B_), dim3(256), 0, stream>>>(Qr, Kr, Vt, attn_out);

  gemm256<float><<<dim3(D_ / 256, (B_ * S_) / 256), dim3(512), 0, stream>>>(
      attn_out, Wdb, out, B_ * S_, D_);
}

// Round 7
// 573.554 us; speedup vs baseline: 1.8962x; 1.0036x over previous
//
#include <hip/hip_runtime.h>

#define B_   2
#define S_   2048
#define D_   4096
#define H_   32
#define KVH_ 8
#define HD_  128
#define NE_  6144   // (KVH*2+H)*HD

using f32x4  = __attribute__((ext_vector_type(4))) float;
using bf16x8 = __attribute__((ext_vector_type(8))) __bf16;

__device__ __forceinline__ unsigned short f2bf(float f) {
  union { float f; unsigned u; } v; v.f = f;
  unsigned r = v.u + 0x7FFFu + ((v.u >> 16) & 1u);
  return (unsigned short)(r >> 16);
}
__device__ __forceinline__ float bf2f(unsigned short h) {
  union { unsigned u; float f; } v; v.u = ((unsigned)h) << 16; return v.f;
}
__device__ __forceinline__ bf16x8 ld8(const unsigned short* p) {
  return *reinterpret_cast<const bf16x8*>(p);
}
__device__ __forceinline__ bf16x8 ld8b(const void* base, int byte_off) {
  return *reinterpret_cast<const bf16x8*>((const char*)base + byte_off);
}
__device__ __forceinline__ void cp16(const void* g, void* l) {
  __builtin_amdgcn_global_load_lds(
      (const __attribute__((address_space(1))) void*)g,
      (__attribute__((address_space(3))) void*)l, 16, 0, 0);
}

// ---------------------------------------------------------------------------
// fp32 -> bf16 (RNE), 4 elems/thread.
// ---------------------------------------------------------------------------
__global__ __launch_bounds__(256) void cvt_f32_bf16(
    const float* __restrict__ in, unsigned short* __restrict__ out, int n4)
{
  int i = blockIdx.x * 256 + threadIdx.x;
  if (i >= n4) return;
  f32x4 v = *reinterpret_cast<const f32x4*>(in + (size_t)i * 4);
  ushort4 o;
  o.x = f2bf(v[0]); o.y = f2bf(v[1]); o.z = f2bf(v[2]); o.w = f2bf(v[3]);
  *reinterpret_cast<ushort4*>(out + (size_t)i * 4) = o;
}

// ---------------------------------------------------------------------------
// 256x256-tile 8-phase GEMM: C[M,N] = A[M,K] * B[N,K]^T, K=4096 fixed.
// (unchanged from round 6: 896 TF on GEMM1 incl. tail, 0 bank conflicts)
// ---------------------------------------------------------------------------
template <typename OutT>
__global__ __launch_bounds__(512, 2) void gemm256(
    const unsigned short* __restrict__ A,
    const unsigned short* __restrict__ Bw,
    OutT* __restrict__ C, int M, int N)
{
  constexpr int K  = 4096;
  constexpr int NI = (K / 64) / 2;   // 32 iterations, 2 K-tiles each
  __shared__ __align__(16) char lds[131072];

  const int tid  = threadIdx.x;
  const int lane = tid & 63;
  const int wave = tid >> 6;
  const int wr = wave >> 2;          // 0..1  (M half)
  const int wc = wave & 3;           // 0..3  (N quarter)
  const int lr = lane & 15;
  const int lk = (lane >> 4) * 8;

  int id  = blockIdx.y * gridDim.x + blockIdx.x;
  const int nwg = gridDim.x * gridDim.y;
  if ((nwg & 7) == 0) { const int q = nwg >> 3; id = (id & 7) * q + (id >> 3); }
  const int row0 = (id / gridDim.x) * 256;
  const int col0 = (id % gridDim.x) * 256;

  int rw[2], cs[2], db[2];
#pragma unroll
  for (int j = 0; j < 2; ++j) {
    db[j] = j * 8192 + tid * 16;
    rw[j] = db[j] >> 7;
    cs[j] = ((db[j] & 127) ^ ((rw[j] & 7) << 4)) >> 1;
  }

  auto stA = [&](int buf, int h, int t) {
#pragma unroll
    for (int j = 0; j < 2; ++j)
      cp16(A + (size_t)(row0 + h * 128 + rw[j]) * K + t * 64 + cs[j],
           lds + buf * 32768 + h * 16384 + db[j]);
  };
  auto stB = [&](int buf, int h, int t) {
#pragma unroll
    for (int j = 0; j < 2; ++j)
      cp16(Bw + (size_t)(col0 + h * 128 + rw[j]) * K + t * 64 + cs[j],
           lds + 65536 + buf * 32768 + h * 16384 + db[j]);
  };

  const int cb0 = ((0 + lk) << 1) ^ ((lr & 7) << 4);
  const int cb1 = ((32 + lk) << 1) ^ ((lr & 7) << 4);
  const int aRowB = (wr * 128 + lr) * 128;
  const int bRowB = (wc * 64 + lr) * 128;

  f32x4 acc[8][4];
#pragma unroll
  for (int m = 0; m < 8; ++m)
#pragma unroll
    for (int n = 0; n < 4; ++n) acc[m][n] = (f32x4){0.f, 0.f, 0.f, 0.f};
  bf16x8 bfr[4][2];

#define FENCE asm volatile("" ::: "memory")
#define VM4   asm volatile("s_waitcnt vmcnt(4)" ::: "memory")
#define VM0   asm volatile("s_waitcnt vmcnt(0)" ::: "memory")

#define PHASE(p, buf, STAGE, WAIT)                                             \
  {                                                                            \
    if ((p) == 0) {                                                            \
      _Pragma("unroll")                                                        \
      for (int n = 0; n < 4; ++n) {                                            \
        bfr[n][0] = ld8b(lds, 65536 + (buf) * 32768 + bRowB + n * 2048 + cb0); \
        bfr[n][1] = ld8b(lds, 65536 + (buf) * 32768 + bRowB + n * 2048 + cb1); \
      }                                                                        \
    }                                                                          \
    bf16x8 a00 = ld8b(lds, (buf) * 32768 + aRowB + ((p) * 2 + 0) * 2048 + cb0);\
    bf16x8 a01 = ld8b(lds, (buf) * 32768 + aRowB + ((p) * 2 + 0) * 2048 + cb1);\
    bf16x8 a10 = ld8b(lds, (buf) * 32768 + aRowB + ((p) * 2 + 1) * 2048 + cb0);\
    bf16x8 a11 = ld8b(lds, (buf) * 32768 + aRowB + ((p) * 2 + 1) * 2048 + cb1);\
    STAGE;                                                                     \
    FENCE;                                                                     \
    __builtin_amdgcn_s_barrier();                                              \
    __builtin_amdgcn_s_setprio(1);                                             \
    _Pragma("unroll")                                                          \
    for (int n = 0; n < 4; ++n) {                                              \
      acc[(p)*2+0][n] = __builtin_amdgcn_mfma_f32_16x16x32_bf16(a00, bfr[n][0], acc[(p)*2+0][n], 0, 0, 0); \
      acc[(p)*2+0][n] = __builtin_amdgcn_mfma_f32_16x16x32_bf16(a01, bfr[n][1], acc[(p)*2+0][n], 0, 0, 0); \
      acc[(p)*2+1][n] = __builtin_amdgcn_mfma_f32_16x16x32_bf16(a10, bfr[n][0], acc[(p)*2+1][n], 0, 0, 0); \
      acc[(p)*2+1][n] = __builtin_amdgcn_mfma_f32_16x16x32_bf16(a11, bfr[n][1], acc[(p)*2+1][n], 0, 0, 0); \
    }                                                                          \
    __builtin_amdgcn_s_setprio(0);                                             \
    WAIT;                                                                      \
    FENCE;                                                                     \
    __builtin_amdgcn_s_barrier();                                              \
  }

  stB(0, 0, 0); stB(0, 1, 0); stA(0, 0, 0); stA(0, 1, 0);
  stB(1, 0, 1); stB(1, 1, 1);
  VM4;
  FENCE;
  __builtin_amdgcn_s_barrier();

  for (int i = 0; i < NI; ++i) {
    const int t1  = 2 * i + 1;
    const int tn0 = 2 * i + 2;
    const int tn1 = 2 * i + 3;
    const bool pre = (i + 1 < NI);
    PHASE(0, 0, { stA(1, 0, t1); }, {});
    PHASE(1, 0, { stA(1, 1, t1); }, {});
    PHASE(2, 0, { if (pre) stB(0, 0, tn0); }, {});
    PHASE(3, 0, { if (pre) stB(0, 1, tn0); },
          { if (pre) { VM4; } else { VM0; } });
    PHASE(0, 1, { if (pre) stA(0, 0, tn0); }, {});
    PHASE(1, 1, { if (pre) stA(0, 1, tn0); }, {});
    PHASE(2, 1, { if (pre) stB(1, 0, tn1); }, {});
    PHASE(3, 1, { if (pre) stB(1, 1, tn1); },
          { if (pre) { VM4; } });
  }
#undef PHASE
#undef FENCE
#undef VM4
#undef VM0

  const int orow = (lane >> 4) * 4;
#pragma unroll
  for (int m = 0; m < 8; ++m) {
    const int gr0 = row0 + wr * 128 + m * 16 + orow;
#pragma unroll
    for (int n = 0; n < 4; ++n) {
      const int gc = col0 + wc * 64 + n * 16 + lr;
#pragma unroll
      for (int r = 0; r < 4; ++r) {
        float val = acc[m][n][r];
        if constexpr (sizeof(OutT) == 2)
          C[(size_t)(gr0 + r) * N + gc] = f2bf(val);
        else
          C[(size_t)(gr0 + r) * N + gc] = val;
      }
    }
  }
}

// ---------------------------------------------------------------------------
// Split fused[B,S,48,128] into Qr (rope), Kr (rope), Vt (transposed).
// ---------------------------------------------------------------------------
__global__ __launch_bounds__(256) void rope_scatter(
    const unsigned short* __restrict__ fused,
    unsigned short* __restrict__ Qr,
    unsigned short* __restrict__ Kr,
    unsigned short* __restrict__ Vt)
{
  int idx = blockIdx.x * 256 + threadIdx.x;  // [0, B*S*48*64)
  int d = idx & 63;
  int t = idx >> 6;
  int e = t % 48;
  int bs = t / 48;
  int s = bs % S_;
  int b = bs / S_;
  int kvh = e / 6, j = e % 6;
  const unsigned short* src = fused + (size_t)bs * NE_ + e * 128;
  unsigned short u1 = src[d];
  unsigned short u2 = src[d + 64];
  if (j == 5) {
    size_t base = (size_t)(b * KVH_ + kvh) * HD_ * S_;
    Vt[base + (size_t)d * S_ + s]        = u1;
    Vt[base + (size_t)(d + 64) * S_ + s] = u2;
  } else {
    float x1 = bf2f(u1), x2 = bf2f(u2);
    float inv = __expf(-(float)d * (9.2103403719761836f / 64.0f));
    float ang = (float)s * inv;
    float sn, c;
    sincosf(ang, &sn, &c);
    float o1 = x1 * c - x2 * sn;
    float o2 = x2 * c + x1 * sn;
    unsigned short* dst;
    if (j == 4) dst = Kr + ((size_t)(b * KVH_ + kvh) * S_ + s) * HD_;
    else        dst = Qr + ((size_t)(b * H_ + kvh * 4 + j) * S_ + s) * HD_;
    dst[d]      = f2bf(o1);
    dst[d + 64] = f2bf(o2);
  }
}

// ---------------------------------------------------------------------------
// Causal GQA flash attention. NOW: K/V double-buffered in LDS, stage(kb+1)
// issued BEFORE compute(kb), one barrier/iter (its vmcnt(0) drain lands the
// prefetch that overlapped the whole compute phase) — same T3-min structure
// that fixed the GEMM in round 5. setprio(1) around MFMA clusters (T5).
// LDS: Kld[2][64x128] swz + Vld[2][128x64] swz + Pld[4][16x64] swz = 72 KB
// -> 2 blocks/CU. Grid 1024 blocks = 2 exact batches, qb-paired balance.
// ---------------------------------------------------------------------------
__global__ __launch_bounds__(256) void attn_fwd(
    const unsigned short* __restrict__ Qr,
    const unsigned short* __restrict__ Kr,
    const unsigned short* __restrict__ Vt,
    unsigned short* __restrict__ O)
{
  __shared__ __align__(16) unsigned short Kld[2][64 * 128];
  __shared__ __align__(16) unsigned short Vld[2][128 * 64];
  __shared__ __align__(16) unsigned short Pld[4][16 * 64];

  const int tid  = threadIdx.x;
  const int lane = tid & 63;
  const int wave = tid >> 6;
  const int bx = blockIdx.x;   // 0..15
  const int h  = blockIdx.y;   // 0..31
  const int b  = blockIdx.z;   // 0..1
  const int kvh = h >> 2;
  const int lr = lane & 15;
  const int lk = (lane >> 4) * 8;
  const int orow = (lane >> 4) * 4;

  const float scale = 0.08838834764831845f;  // 1/sqrt(128)
  const unsigned short* Kb = Kr + (size_t)(b * KVH_ + kvh) * S_ * HD_;
  const unsigned short* Vb = Vt + (size_t)(b * KVH_ + kvh) * HD_ * S_;

  // Stage K/V tile kb into buffer `buf`. Linear LDS dest (wave-uniform base,
  // HW adds lane*16), inverse-swizzled global source column (rule #21).
  auto stage = [&](int buf, int kb) {
#pragma unroll
    for (int i = 0; i < 4; ++i) {
      const int db = i * 4096 + tid * 16;
      {  // K: 256 B/row
        const int row  = db >> 8;
        const int colb = (db & 255) ^ ((row & 7) << 4);
        cp16(Kb + (size_t)(kb * 64 + row) * HD_ + (colb >> 1),
             (char*)&Kld[buf][0] + i * 4096 + wave * 1024);
      }
      {  // V: 128 B/row
        const int row  = db >> 7;
        const int colb = (db & 127) ^ ((row & 7) << 4);
        cp16(Vb + (size_t)row * S_ + kb * 64 + (colb >> 1),
             (char*)&Vld[buf][0] + i * 4096 + wave * 1024);
      }
    }
  };

  for (int half = 0; half < 2; ++half) {
    const int qb = half ? (S_ / 64 - 1 - bx) : bx;

    const unsigned short* qbase =
        Qr + ((size_t)(b * H_ + h) * S_ + qb * 64 + wave * 16 + lr) * HD_;
    bf16x8 qf[4];
#pragma unroll
    for (int t = 0; t < 4; ++t) qf[t] = ld8(qbase + t * 32 + lk);

    f32x4 acc_o[8];
#pragma unroll
    for (int dt = 0; dt < 8; ++dt) acc_o[dt] = (f32x4){0.f, 0.f, 0.f, 0.f};
    float mrow[4], lrow[4];
#pragma unroll
    for (int r = 0; r < 4; ++r) { mrow[r] = -1e30f; lrow[r] = 0.f; }

    stage(0, 0);
    __syncthreads();   // drains prologue stage

    for (int kb = 0; kb <= qb; ++kb) {
      const int cur = kb & 1;
      if (kb < qb) stage(cur ^ 1, kb + 1);   // prefetch next tile FIRST

      const char* Kc = (const char*)&Kld[cur][0];
      const char* Vc = (const char*)&Vld[cur][0];

      // S = Q K^T for this wave's 16 rows x 64 cols
      f32x4 accs[4];
#pragma unroll
      for (int kt = 0; kt < 4; ++kt) accs[kt] = (f32x4){0.f, 0.f, 0.f, 0.f};
      __builtin_amdgcn_s_setprio(1);
#pragma unroll
      for (int t = 0; t < 4; ++t) {
#pragma unroll
        for (int kt = 0; kt < 4; ++kt) {
          const int krow = kt * 16 + lr;
          const int kbyte = ((krow << 8) + ((t * 32 + lk) << 1)) ^ ((krow & 7) << 4);
          bf16x8 kf = ld8b(Kc, kbyte);
          accs[kt] = __builtin_amdgcn_mfma_f32_16x16x32_bf16(qf[t], kf, accs[kt], 0, 0, 0);
        }
      }
      __builtin_amdgcn_s_setprio(0);

      const bool last = (kb == qb);
      float sv[4][4];
#pragma unroll
      for (int r = 0; r < 4; ++r) {
        const int qg = qb * 64 + wave * 16 + orow + r;
#pragma unroll
        for (int kt = 0; kt < 4; ++kt) {
          float v = accs[kt][r] * scale;
          int kg = kb * 64 + kt * 16 + lr;
          if (last && kg > qg) v = -1e30f;
          sv[r][kt] = v;
        }
      }

      float mnew[4], corr[4];
#pragma unroll
      for (int r = 0; r < 4; ++r) {
        float mx = fmaxf(fmaxf(sv[r][0], sv[r][1]), fmaxf(sv[r][2], sv[r][3]));
#pragma unroll
        for (int msk = 8; msk >= 1; msk >>= 1) mx = fmaxf(mx, __shfl_xor(mx, msk, 64));
        mnew[r] = fmaxf(mrow[r], mx);
        corr[r] = __expf(mrow[r] - mnew[r]);
        mrow[r] = mnew[r];
      }
#pragma unroll
      for (int r = 0; r < 4; ++r) {
        float su = 0.f;
#pragma unroll
        for (int kt = 0; kt < 4; ++kt) {
          float p = __expf(sv[r][kt] - mnew[r]);
          su += p;
          const int prow = orow + r;
          const int pbyte = ((prow << 7) + ((kt * 16 + lr) << 1)) ^ ((prow & 7) << 4);
          *(unsigned short*)((char*)&Pld[wave][0] + pbyte) = f2bf(p);
        }
#pragma unroll
        for (int msk = 8; msk >= 1; msk >>= 1) su += __shfl_xor(su, msk, 64);
        lrow[r] = lrow[r] * corr[r] + su;
      }
#pragma unroll
      for (int dt = 0; dt < 8; ++dt)
#pragma unroll
        for (int r = 0; r < 4; ++r) acc_o[dt][r] *= corr[r];

      // Compiler fence: Pld written as ushort, read as bf16x8 below (TBAA).
      asm volatile("" ::: "memory");

      // O += P V
      __builtin_amdgcn_s_setprio(1);
#pragma unroll
      for (int kc = 0; kc < 2; ++kc) {
        const int pbyte = ((lr << 7) + ((kc * 32 + lk) << 1)) ^ ((lr & 7) << 4);
        bf16x8 pf = ld8b(&Pld[wave][0], pbyte);
#pragma unroll
        for (int dt = 0; dt < 8; ++dt) {
          const int vrow = dt * 16 + lr;
          const int vbyte = ((vrow << 7) + ((kc * 32 + lk) << 1)) ^ ((vrow & 7) << 4);
          bf16x8 vf = ld8b(Vc, vbyte);
          acc_o[dt] = __builtin_amdgcn_mfma_f32_16x16x32_bf16(pf, vf, acc_o[dt], 0, 0, 0);
        }
      }
      __builtin_amdgcn_s_setprio(0);

      __syncthreads();  // lands prefetch (vmcnt drain) + separates buf reuse
    }

#pragma unroll
    for (int r = 0; r < 4; ++r) {
      float inv = 1.f / lrow[r];
      size_t rowoff =
          (size_t)(b * S_ + qb * 64 + wave * 16 + orow + r) * (H_ * HD_) + h * HD_;
#pragma unroll
      for (int dt = 0; dt < 8; ++dt)
        O[rowoff + dt * 16 + lr] = f2bf(acc_o[dt][r] * inv);
    }
  }
}

// Diagnostic: if ws_size is too small, fill fp32 output with sentinel 12345.
__global__ void fill_sentinel(float* __restrict__ O, int n) {
  int i = blockIdx.x * 256 + threadIdx.x;
  if (i < n) O[i] = 12345.0f;
}

// ---------------------------------------------------------------------------
extern "C" void kernel_launch(void* const* d_in, const int* in_sizes, int n_in,
                              void* d_out, int out_size, void* d_ws, size_t ws_size,
                              hipStream_t stream) {
  const float* hidden = (const float*)d_in[0]; // [B,S,D] fp32
  const float* wqkv   = (const float*)d_in[1]; // [6144,4096] fp32
  const float* wdense = (const float*)d_in[2]; // [4096,4096] fp32
  float* out = (float*)d_out;                  // [B,S,4096] fp32

  const size_t NEED = 134217728;
  if (ws_size < NEED) {
    fill_sentinel<<<dim3((out_size + 255) / 256), dim3(256), 0, stream>>>(out, out_size);
    return;
  }

  char* ws = (char*)d_ws;
  // Phase 1 layout
  unsigned short* Hb    = (unsigned short*)(ws);                 // 33,554,432 B
  unsigned short* Wqb   = (unsigned short*)(ws + 33554432);      // 50,331,648 B
  unsigned short* fused = (unsigned short*)(ws + 83886080);      // 50,331,648 B
  // Phase 2 layout (after GEMM1: Hb/Wqb dead)
  unsigned short* Qr    = (unsigned short*)(ws);                 // 33,554,432 B
  unsigned short* Kr    = (unsigned short*)(ws + 33554432);      //  8,388,608 B
  unsigned short* Vt    = (unsigned short*)(ws + 41943040);      //  8,388,608 B
  unsigned short* Wdb   = (unsigned short*)(ws + 50331648);      // 33,554,432 B
  unsigned short* attn_out = (unsigned short*)(ws + 83886080);   // 33,554,432 B (over fused)

  const int nH = B_ * S_ * D_;      // 16,777,216
  const int nQ = NE_ * D_;          // 25,165,824
  const int nD = D_ * D_;           // 16,777,216

  cvt_f32_bf16<<<dim3(nH / 4 / 256), dim3(256), 0, stream>>>(hidden, Hb, nH / 4);
  cvt_f32_bf16<<<dim3(nQ / 4 / 256), dim3(256), 0, stream>>>(wqkv, Wqb, nQ / 4);

  gemm256<unsigned short><<<dim3(NE_ / 256, (B_ * S_) / 256), dim3(512), 0, stream>>>(
      Hb, Wqb, fused, B_ * S_, NE_);

  cvt_f32_bf16<<<dim3(nD / 4 / 256), dim3(256), 0, stream>>>(wdense, Wdb, nD / 4);

  rope_scatter<<<dim3((B_ * S_ * 48 * 64) / 256), dim3(256), 0, stream>>>(
      fused, Qr, Kr, Vt);

  attn_fwd<<<dim3(16, H_, B_), dim3(256), 0, stream>>>(Qr, Kr, Vt, attn_out);

  gemm256<float><<<dim3(D_ / 256, (B_ * S_) / 256), dim3(512), 0, stream>>>(
      attn_out, Wdb, out, B_ * S_, D_);
}

// Round 9
// 560.383 us; speedup vs baseline: 1.9407x; 1.0235x over previous
//
#include <hip/hip_runtime.h>

#define B_   2
#define S_   2048
#define D_   4096
#define H_   32
#define KVH_ 8
#define HD_  128
#define NE_  6144   // (KVH*2+H)*HD

using f32x4  = __attribute__((ext_vector_type(4))) float;
using bf16x8 = __attribute__((ext_vector_type(8))) __bf16;

__device__ __forceinline__ unsigned short f2bf(float f) {
  union { float f; unsigned u; } v; v.f = f;
  unsigned r = v.u + 0x7FFFu + ((v.u >> 16) & 1u);
  return (unsigned short)(r >> 16);
}
__device__ __forceinline__ float bf2f(unsigned short h) {
  union { unsigned u; float f; } v; v.u = ((unsigned)h) << 16; return v.f;
}
__device__ __forceinline__ bf16x8 ld8(const unsigned short* p) {
  return *reinterpret_cast<const bf16x8*>(p);
}
__device__ __forceinline__ bf16x8 ld8b(const void* base, int byte_off) {
  return *reinterpret_cast<const bf16x8*>((const char*)base + byte_off);
}
__device__ __forceinline__ void cp16(const void* g, void* l) {
  __builtin_amdgcn_global_load_lds(
      (const __attribute__((address_space(1))) void*)g,
      (__attribute__((address_space(3))) void*)l, 16, 0, 0);
}

// ---------------------------------------------------------------------------
// fp32 -> bf16 (RNE), 4 elems/thread. Single-segment.
// ---------------------------------------------------------------------------
__global__ __launch_bounds__(256) void cvt_f32_bf16(
    const float* __restrict__ in, unsigned short* __restrict__ out, int n4)
{
  int i = blockIdx.x * 256 + threadIdx.x;
  if (i >= n4) return;
  f32x4 v = *reinterpret_cast<const f32x4*>(in + (size_t)i * 4);
  ushort4 o;
  o.x = f2bf(v[0]); o.y = f2bf(v[1]); o.z = f2bf(v[2]); o.w = f2bf(v[3]);
  *reinterpret_cast<ushort4*>(out + (size_t)i * 4) = o;
}

// Two segments in one launch (dests must be disjoint!).
__global__ __launch_bounds__(256) void cvt2_f32_bf16(
    const float* __restrict__ s0, unsigned short* __restrict__ d0, int n0,
    const float* __restrict__ s1, unsigned short* __restrict__ d1, int n1)
{
  int i = blockIdx.x * 256 + threadIdx.x;
  const float* src; unsigned short* dst;
  if (i < n0) { src = s0; dst = d0; }
  else        { i -= n0; if (i >= n1) return; src = s1; dst = d1; }
  f32x4 v = *reinterpret_cast<const f32x4*>(src + (size_t)i * 4);
  ushort4 o;
  o.x = f2bf(v[0]); o.y = f2bf(v[1]); o.z = f2bf(v[2]); o.w = f2bf(v[3]);
  *reinterpret_cast<ushort4*>(dst + (size_t)i * 4) = o;
}

// ---------------------------------------------------------------------------
// 256xNT-tile 8-phase GEMM: C[M,N] = A[M,K] * B[N,K]^T, K=4096 fixed.
// NT in {192, 256}. 8 waves (2M x 4N), per-wave C = 128 x NT/4. BK=64,
// 2 K-tiles/iter, 8 phases. B staged in NB=NT/64 chunks of 8KB (1 load/thr),
// A in 2 halves of 16KB (2 loads/thr). Counted vmcnt(NB) at P4/P8 (T4
// formula: allowed-in-flight = next tile's B chunks). LDS XOR-swizzle
// byte^=(row&7)<<4 via inverse-swizzled global source (rule #21).
// NT=256 instantiation == round-6's passing schedule (regression anchor).
// ---------------------------------------------------------------------------
template <typename OutT, int NT>
__global__ __launch_bounds__(512, 2) void gemm256(
    const unsigned short* __restrict__ A,
    const unsigned short* __restrict__ Bw,
    OutT* __restrict__ C, int M, int N)
{
  constexpr int K  = 4096;
  constexpr int NI = (K / 64) / 2;     // 32 iterations, 2 K-tiles each
  constexpr int NB = NT / 64;          // B chunks per tile (3 or 4)
  constexpr int NN = NT / 64;          // n-frags per wave
  constexpr int WN = NT / 4;           // per-wave N extent
  constexpr int BBUF = NT * 128;       // B bytes per buffer
  __shared__ __align__(16) char lds[65536 + 2 * BBUF];

  const int tid  = threadIdx.x;
  const int lane = tid & 63;
  const int wave = tid >> 6;
  const int wr = wave >> 2;            // 0..1  (M half)
  const int wc = wave & 3;             // 0..3  (N quarter)
  const int lr = lane & 15;
  const int lk = (lane >> 4) * 8;

  int id  = blockIdx.y * gridDim.x + blockIdx.x;
  const int nwg = gridDim.x * gridDim.y;
  if ((nwg & 7) == 0) { const int q = nwg >> 3; id = (id & 7) * q + (id >> 3); }
  const int row0 = (id / gridDim.x) * 256;
  const int col0 = (id % gridDim.x) * NT;

  // A staging: 2 halves x 2 loads/thread (16KB each).
  int rwA[2], csA[2], dbA[2];
#pragma unroll
  for (int j = 0; j < 2; ++j) {
    dbA[j] = j * 8192 + tid * 16;
    rwA[j] = dbA[j] >> 7;
    csA[j] = ((dbA[j] & 127) ^ ((rwA[j] & 7) << 4)) >> 1;
  }
  auto stA = [&](int buf, int h, int t) {
#pragma unroll
    for (int j = 0; j < 2; ++j)
      cp16(A + (size_t)(row0 + h * 128 + rwA[j]) * K + t * 64 + csA[j],
           lds + buf * 32768 + h * 16384 + dbA[j]);
  };
  // B staging: NB chunks x 1 load/thread (8KB each, 64 rows).
  const int dbB = tid * 16;
  const int rwB = dbB >> 7;                              // 0..63
  const int csB = ((dbB & 127) ^ ((rwB & 7) << 4)) >> 1; // chunk row base %8==0
  auto stB = [&](int buf, int c, int t) {
    cp16(Bw + (size_t)(col0 + c * 64 + rwB) * K + t * 64 + csB,
         lds + 65536 + buf * BBUF + c * 8192 + dbB);
  };

  const int cb0 = ((0 + lk) << 1) ^ ((lr & 7) << 4);
  const int cb1 = ((32 + lk) << 1) ^ ((lr & 7) << 4);
  const int aRowB = (wr * 128 + lr) * 128;
  const int bRowB = (wc * WN + lr) * 128;

  f32x4 acc[8][NN];
#pragma unroll
  for (int m = 0; m < 8; ++m)
#pragma unroll
    for (int n = 0; n < NN; ++n) acc[m][n] = (f32x4){0.f, 0.f, 0.f, 0.f};
  bf16x8 bfr[NN][2];

#define FENCE asm volatile("" ::: "memory")
#define VMNB  do { if constexpr (NB == 4) asm volatile("s_waitcnt vmcnt(4)" ::: "memory"); \
                   else                   asm volatile("s_waitcnt vmcnt(3)" ::: "memory"); } while (0)
#define VM0   asm volatile("s_waitcnt vmcnt(0)" ::: "memory")

#define PHASE(p, buf, STAGE, WAIT)                                             \
  {                                                                            \
    if ((p) == 0) {                                                            \
      _Pragma("unroll")                                                        \
      for (int n = 0; n < NN; ++n) {                                           \
        bfr[n][0] = ld8b(lds, 65536 + (buf) * BBUF + bRowB + n * 2048 + cb0);  \
        bfr[n][1] = ld8b(lds, 65536 + (buf) * BBUF + bRowB + n * 2048 + cb1);  \
      }                                                                        \
    }                                                                          \
    bf16x8 a00 = ld8b(lds, (buf) * 32768 + aRowB + ((p) * 2 + 0) * 2048 + cb0);\
    bf16x8 a01 = ld8b(lds, (buf) * 32768 + aRowB + ((p) * 2 + 0) * 2048 + cb1);\
    bf16x8 a10 = ld8b(lds, (buf) * 32768 + aRowB + ((p) * 2 + 1) * 2048 + cb0);\
    bf16x8 a11 = ld8b(lds, (buf) * 32768 + aRowB + ((p) * 2 + 1) * 2048 + cb1);\
    STAGE;                                                                     \
    FENCE;                                                                     \
    __builtin_amdgcn_s_barrier();                                              \
    __builtin_amdgcn_s_setprio(1);                                             \
    _Pragma("unroll")                                                          \
    for (int n = 0; n < NN; ++n) {                                             \
      acc[(p)*2+0][n] = __builtin_amdgcn_mfma_f32_16x16x32_bf16(a00, bfr[n][0], acc[(p)*2+0][n], 0, 0, 0); \
      acc[(p)*2+0][n] = __builtin_amdgcn_mfma_f32_16x16x32_bf16(a01, bfr[n][1], acc[(p)*2+0][n], 0, 0, 0); \
      acc[(p)*2+1][n] = __builtin_amdgcn_mfma_f32_16x16x32_bf16(a10, bfr[n][0], acc[(p)*2+1][n], 0, 0, 0); \
      acc[(p)*2+1][n] = __builtin_amdgcn_mfma_f32_16x16x32_bf16(a11, bfr[n][1], acc[(p)*2+1][n], 0, 0, 0); \
    }                                                                          \
    __builtin_amdgcn_s_setprio(0);                                             \
    WAIT;                                                                      \
    FENCE;                                                                     \
    __builtin_amdgcn_s_barrier();                                              \
  }

  // Prologue: tile0 B+A into buf0, tile1 B into buf1; allow tile1-B in flight.
#pragma unroll
  for (int c = 0; c < NB; ++c) stB(0, c, 0);
  stA(0, 0, 0); stA(0, 1, 0);
#pragma unroll
  for (int c = 0; c < NB; ++c) stB(1, c, 1);
  VMNB;
  FENCE;
  __builtin_amdgcn_s_barrier();

  for (int i = 0; i < NI; ++i) {
    const int t1  = 2 * i + 1;
    const int tn0 = 2 * i + 2;
    const int tn1 = 2 * i + 3;
    const bool pre = (i + 1 < NI);
    // K-tile 2i in buf0
    PHASE(0, 0, { stA(1, 0, t1); }, {});
    PHASE(1, 0, { stA(1, 1, t1); }, {});
    PHASE(2, 0, { if (pre) { stB(0, 0, tn0); stB(0, 1, tn0); } }, {});
    PHASE(3, 0, { if (pre) { _Pragma("unroll") for (int c = 2; c < NB; ++c) stB(0, c, tn0); } },
          { if (pre) { VMNB; } else { VM0; } });
    // K-tile 2i+1 in buf1
    PHASE(0, 1, { if (pre) stA(0, 0, tn0); }, {});
    PHASE(1, 1, { if (pre) stA(0, 1, tn0); }, {});
    PHASE(2, 1, { if (pre) { stB(1, 0, tn1); stB(1, 1, tn1); } }, {});
    PHASE(3, 1, { if (pre) { _Pragma("unroll") for (int c = 2; c < NB; ++c) stB(1, c, tn1); } },
          { if (pre) { VMNB; } });
  }
#undef PHASE
#undef FENCE
#undef VMNB
#undef VM0

  const int orow = (lane >> 4) * 4;
#pragma unroll
  for (int m = 0; m < 8; ++m) {
    const int gr0 = row0 + wr * 128 + m * 16 + orow;
#pragma unroll
    for (int n = 0; n < NN; ++n) {
      const int gc = col0 + wc * WN + n * 16 + lr;
#pragma unroll
      for (int r = 0; r < 4; ++r) {
        float val = acc[m][n][r];
        if constexpr (sizeof(OutT) == 2)
          C[(size_t)(gr0 + r) * N + gc] = f2bf(val);
        else
          C[(size_t)(gr0 + r) * N + gc] = val;
      }
    }
  }
}

// ---------------------------------------------------------------------------
// Split fused[B,S,48,128] into Qr (rope), Kr (rope), Vt (transposed).
// ---------------------------------------------------------------------------
__global__ __launch_bounds__(256) void rope_scatter(
    const unsigned short* __restrict__ fused,
    unsigned short* __restrict__ Qr,
    unsigned short* __restrict__ Kr,
    unsigned short* __restrict__ Vt)
{
  int idx = blockIdx.x * 256 + threadIdx.x;  // [0, B*S*48*64)
  int d = idx & 63;
  int t = idx >> 6;
  int e = t % 48;
  int bs = t / 48;
  int s = bs % S_;
  int b = bs / S_;
  int kvh = e / 6, j = e % 6;
  const unsigned short* src = fused + (size_t)bs * NE_ + e * 128;
  unsigned short u1 = src[d];
  unsigned short u2 = src[d + 64];
  if (j == 5) {
    size_t base = (size_t)(b * KVH_ + kvh) * HD_ * S_;
    Vt[base + (size_t)d * S_ + s]        = u1;
    Vt[base + (size_t)(d + 64) * S_ + s] = u2;
  } else {
    float x1 = bf2f(u1), x2 = bf2f(u2);
    float inv = __expf(-(float)d * (9.2103403719761836f / 64.0f));
    float ang = (float)s * inv;
    float sn, c;
    sincosf(ang, &sn, &c);
    float o1 = x1 * c - x2 * sn;
    float o2 = x2 * c + x1 * sn;
    unsigned short* dst;
    if (j == 4) dst = Kr + ((size_t)(b * KVH_ + kvh) * S_ + s) * HD_;
    else        dst = Qr + ((size_t)(b * H_ + kvh * 4 + j) * S_ + s) * HD_;
    dst[d]      = f2bf(o1);
    dst[d + 64] = f2bf(o2);
  }
}

// ---------------------------------------------------------------------------
// Causal GQA flash attention (round-7 structure, unchanged).
// ---------------------------------------------------------------------------
__global__ __launch_bounds__(256) void attn_fwd(
    const unsigned short* __restrict__ Qr,
    const unsigned short* __restrict__ Kr,
    const unsigned short* __restrict__ Vt,
    unsigned short* __restrict__ O)
{
  __shared__ __align__(16) unsigned short Kld[2][64 * 128];
  __shared__ __align__(16) unsigned short Vld[2][128 * 64];
  __shared__ __align__(16) unsigned short Pld[4][16 * 64];

  const int tid  = threadIdx.x;
  const int lane = tid & 63;
  const int wave = tid >> 6;
  const int bx = blockIdx.x;   // 0..15
  const int h  = blockIdx.y;   // 0..31
  const int b  = blockIdx.z;   // 0..1
  const int kvh = h >> 2;
  const int lr = lane & 15;
  const int lk = (lane >> 4) * 8;
  const int orow = (lane >> 4) * 4;

  const float scale = 0.08838834764831845f;  // 1/sqrt(128)
  const unsigned short* Kb = Kr + (size_t)(b * KVH_ + kvh) * S_ * HD_;
  const unsigned short* Vb = Vt + (size_t)(b * KVH_ + kvh) * HD_ * S_;

  auto stage = [&](int buf, int kb) {
#pragma unroll
    for (int i = 0; i < 4; ++i) {
      const int db = i * 4096 + tid * 16;
      {  // K: 256 B/row
        const int row  = db >> 8;
        const int colb = (db & 255) ^ ((row & 7) << 4);
        cp16(Kb + (size_t)(kb * 64 + row) * HD_ + (colb >> 1),
             (char*)&Kld[buf][0] + i * 4096 + wave * 1024);
      }
      {  // V: 128 B/row
        const int row  = db >> 7;
        const int colb = (db & 127) ^ ((row & 7) << 4);
        cp16(Vb + (size_t)row * S_ + kb * 64 + (colb >> 1),
             (char*)&Vld[buf][0] + i * 4096 + wave * 1024);
      }
    }
  };

  for (int half = 0; half < 2; ++half) {
    const int qb = half ? (S_ / 64 - 1 - bx) : bx;

    const unsigned short* qbase =
        Qr + ((size_t)(b * H_ + h) * S_ + qb * 64 + wave * 16 + lr) * HD_;
    bf16x8 qf[4];
#pragma unroll
    for (int t = 0; t < 4; ++t) qf[t] = ld8(qbase + t * 32 + lk);

    f32x4 acc_o[8];
#pragma unroll
    for (int dt = 0; dt < 8; ++dt) acc_o[dt] = (f32x4){0.f, 0.f, 0.f, 0.f};
    float mrow[4], lrow[4];
#pragma unroll
    for (int r = 0; r < 4; ++r) { mrow[r] = -1e30f; lrow[r] = 0.f; }

    stage(0, 0);
    __syncthreads();

    for (int kb = 0; kb <= qb; ++kb) {
      const int cur = kb & 1;
      if (kb < qb) stage(cur ^ 1, kb + 1);

      const char* Kc = (const char*)&Kld[cur][0];
      const char* Vc = (const char*)&Vld[cur][0];

      f32x4 accs[4];
#pragma unroll
      for (int kt = 0; kt < 4; ++kt) accs[kt] = (f32x4){0.f, 0.f, 0.f, 0.f};
      __builtin_amdgcn_s_setprio(1);
#pragma unroll
      for (int t = 0; t < 4; ++t) {
#pragma unroll
        for (int kt = 0; kt < 4; ++kt) {
          const int krow = kt * 16 + lr;
          const int kbyte = ((krow << 8) + ((t * 32 + lk) << 1)) ^ ((krow & 7) << 4);
          bf16x8 kf = ld8b(Kc, kbyte);
          accs[kt] = __builtin_amdgcn_mfma_f32_16x16x32_bf16(qf[t], kf, accs[kt], 0, 0, 0);
        }
      }
      __builtin_amdgcn_s_setprio(0);

      const bool last = (kb == qb);
      float sv[4][4];
#pragma unroll
      for (int r = 0; r < 4; ++r) {
        const int qg = qb * 64 + wave * 16 + orow + r;
#pragma unroll
        for (int kt = 0; kt < 4; ++kt) {
          float v = accs[kt][r] * scale;
          int kg = kb * 64 + kt * 16 + lr;
          if (last && kg > qg) v = -1e30f;
          sv[r][kt] = v;
        }
      }

      float mnew[4], corr[4];
#pragma unroll
      for (int r = 0; r < 4; ++r) {
        float mx = fmaxf(fmaxf(sv[r][0], sv[r][1]), fmaxf(sv[r][2], sv[r][3]));
#pragma unroll
        for (int msk = 8; msk >= 1; msk >>= 1) mx = fmaxf(mx, __shfl_xor(mx, msk, 64));
        mnew[r] = fmaxf(mrow[r], mx);
        corr[r] = __expf(mrow[r] - mnew[r]);
        mrow[r] = mnew[r];
      }
#pragma unroll
      for (int r = 0; r < 4; ++r) {
        float su = 0.f;
#pragma unroll
        for (int kt = 0; kt < 4; ++kt) {
          float p = __expf(sv[r][kt] - mnew[r]);
          su += p;
          const int prow = orow + r;
          const int pbyte = ((prow << 7) + ((kt * 16 + lr) << 1)) ^ ((prow & 7) << 4);
          *(unsigned short*)((char*)&Pld[wave][0] + pbyte) = f2bf(p);
        }
#pragma unroll
        for (int msk = 8; msk >= 1; msk >>= 1) su += __shfl_xor(su, msk, 64);
        lrow[r] = lrow[r] * corr[r] + su;
      }
#pragma unroll
      for (int dt = 0; dt < 8; ++dt)
#pragma unroll
        for (int r = 0; r < 4; ++r) acc_o[dt][r] *= corr[r];

      asm volatile("" ::: "memory");

      __builtin_amdgcn_s_setprio(1);
#pragma unroll
      for (int kc = 0; kc < 2; ++kc) {
        const int pbyte = ((lr << 7) + ((kc * 32 + lk) << 1)) ^ ((lr & 7) << 4);
        bf16x8 pf = ld8b(&Pld[wave][0], pbyte);
#pragma unroll
        for (int dt = 0; dt < 8; ++dt) {
          const int vrow = dt * 16 + lr;
          const int vbyte = ((vrow << 7) + ((kc * 32 + lk) << 1)) ^ ((vrow & 7) << 4);
          bf16x8 vf = ld8b(Vc, vbyte);
          acc_o[dt] = __builtin_amdgcn_mfma_f32_16x16x32_bf16(pf, vf, acc_o[dt], 0, 0, 0);
        }
      }
      __builtin_amdgcn_s_setprio(0);

      __syncthreads();
    }

#pragma unroll
    for (int r = 0; r < 4; ++r) {
      float inv = 1.f / lrow[r];
      size_t rowoff =
          (size_t)(b * S_ + qb * 64 + wave * 16 + orow + r) * (H_ * HD_) + h * HD_;
#pragma unroll
      for (int dt = 0; dt < 8; ++dt)
        O[rowoff + dt * 16 + lr] = f2bf(acc_o[dt][r] * inv);
    }
  }
}

// Diagnostic: if ws_size is too small, fill fp32 output with sentinel 12345.
__global__ void fill_sentinel(float* __restrict__ O, int n) {
  int i = blockIdx.x * 256 + threadIdx.x;
  if (i < n) O[i] = 12345.0f;
}

// ---------------------------------------------------------------------------
extern "C" void kernel_launch(void* const* d_in, const int* in_sizes, int n_in,
                              void* d_out, int out_size, void* d_ws, size_t ws_size,
                              hipStream_t stream) {
  const float* hidden = (const float*)d_in[0]; // [B,S,D] fp32
  const float* wqkv   = (const float*)d_in[1]; // [6144,4096] fp32
  const float* wdense = (const float*)d_in[2]; // [4096,4096] fp32
  float* out = (float*)d_out;                  // [B,S,4096] fp32

  const size_t NEED = 134217728;
  if (ws_size < NEED) {
    fill_sentinel<<<dim3((out_size + 255) / 256), dim3(256), 0, stream>>>(out, out_size);
    return;
  }

  char* ws = (char*)d_ws;
  // Phase 1 layout
  unsigned short* Hb    = (unsigned short*)(ws);                 // 33,554,432 B
  unsigned short* Wqb   = (unsigned short*)(ws + 33554432);      // 50,331,648 B
  unsigned short* fused = (unsigned short*)(ws + 83886080);      // 50,331,648 B
  // Phase 2 layout (after GEMM1: Hb/Wqb dead; Wdb sequenced AFTER GEMM1!)
  unsigned short* Qr    = (unsigned short*)(ws);                 // 33,554,432 B
  unsigned short* Kr    = (unsigned short*)(ws + 33554432);      //  8,388,608 B
  unsigned short* Vt    = (unsigned short*)(ws + 41943040);      //  8,388,608 B
  unsigned short* Wdb   = (unsigned short*)(ws + 50331648);      // 33,554,432 B
  unsigned short* attn_out = (unsigned short*)(ws + 83886080);   // 33,554,432 B (over fused)

  const int nH4 = B_ * S_ * D_ / 4;   // 4,194,304
  const int nQ4 = NE_ * D_ / 4;       // 6,291,456
  const int nD4 = D_ * D_ / 4;        // 4,194,304

  // hidden+wqkv conversions (disjoint dests) in one launch.
  cvt2_f32_bf16<<<dim3((nH4 + nQ4 + 255) / 256), dim3(256), 0, stream>>>(
      hidden, Hb, nH4, wqkv, Wqb, nQ4);

  gemm256<unsigned short, 192><<<dim3(NE_ / 192, (B_ * S_) / 256), dim3(512), 0, stream>>>(
      Hb, Wqb, fused, B_ * S_, NE_);

  // wdense conversion AFTER GEMM1 (Wdb overlays dead Wqb tail).
  cvt_f32_bf16<<<dim3(nD4 / 256), dim3(256), 0, stream>>>(wdense, Wdb, nD4);

  rope_scatter<<<dim3((B_ * S_ * 48 * 64) / 256), dim3(256), 0, stream>>>(
      fused, Qr, Kr, Vt);

  attn_fwd<<<dim3(16, H_, B_), dim3(256), 0, stream>>>(Qr, Kr, Vt, attn_out);

  gemm256<float, 256><<<dim3(D_ / 256, (B_ * S_) / 256), dim3(512), 0, stream>>>(
      attn_out, Wdb, out, B_ * S_, D_);
}

// Round 10
// 527.437 us; speedup vs baseline: 2.0620x; 1.0625x over previous
//
#include <hip/hip_runtime.h>

#define B_   2
#define S_   2048
#define D_   4096
#define H_   32
#define KVH_ 8
#define HD_  128
#define NE_  6144   // (KVH*2+H)*HD

using f32x4  = __attribute__((ext_vector_type(4))) float;
using bf16x8 = __attribute__((ext_vector_type(8))) __bf16;

__device__ __forceinline__ unsigned short f2bf(float f) {
  union { float f; unsigned u; } v; v.f = f;
  unsigned r = v.u + 0x7FFFu + ((v.u >> 16) & 1u);
  return (unsigned short)(r >> 16);
}
__device__ __forceinline__ float bf2f(unsigned short h) {
  union { unsigned u; float f; } v; v.u = ((unsigned)h) << 16; return v.f;
}
__device__ __forceinline__ bf16x8 ld8(const unsigned short* p) {
  return *reinterpret_cast<const bf16x8*>(p);
}
__device__ __forceinline__ bf16x8 ld8b(const void* base, int byte_off) {
  return *reinterpret_cast<const bf16x8*>((const char*)base + byte_off);
}
__device__ __forceinline__ void cp16(const void* g, void* l) {
  __builtin_amdgcn_global_load_lds(
      (const __attribute__((address_space(1))) void*)g,
      (__attribute__((address_space(3))) void*)l, 16, 0, 0);
}
__device__ __forceinline__ float exp2a(float x) {   // 2^x via v_exp_f32
  float r; asm("v_exp_f32 %0, %1" : "=v"(r) : "v"(x)); return r;
}

// ---------------------------------------------------------------------------
// fp32 -> bf16 (RNE), 4 elems/thread. Single-segment.
// ---------------------------------------------------------------------------
__global__ __launch_bounds__(256) void cvt_f32_bf16(
    const float* __restrict__ in, unsigned short* __restrict__ out, int n4)
{
  int i = blockIdx.x * 256 + threadIdx.x;
  if (i >= n4) return;
  f32x4 v = *reinterpret_cast<const f32x4*>(in + (size_t)i * 4);
  ushort4 o;
  o.x = f2bf(v[0]); o.y = f2bf(v[1]); o.z = f2bf(v[2]); o.w = f2bf(v[3]);
  *reinterpret_cast<ushort4*>(out + (size_t)i * 4) = o;
}

// Two segments in one launch (dests must be disjoint!).
__global__ __launch_bounds__(256) void cvt2_f32_bf16(
    const float* __restrict__ s0, unsigned short* __restrict__ d0, int n0,
    const float* __restrict__ s1, unsigned short* __restrict__ d1, int n1)
{
  int i = blockIdx.x * 256 + threadIdx.x;
  const float* src; unsigned short* dst;
  if (i < n0) { src = s0; dst = d0; }
  else        { i -= n0; if (i >= n1) return; src = s1; dst = d1; }
  f32x4 v = *reinterpret_cast<const f32x4*>(src + (size_t)i * 4);
  ushort4 o;
  o.x = f2bf(v[0]); o.y = f2bf(v[1]); o.z = f2bf(v[2]); o.w = f2bf(v[3]);
  *reinterpret_cast<ushort4*>(dst + (size_t)i * 4) = o;
}

// ---------------------------------------------------------------------------
// 256xNT-tile 8-phase GEMM: C[M,N] = A[M,K] * B[N,K]^T, K=4096 fixed.
// (unchanged from round 9)
// ---------------------------------------------------------------------------
template <typename OutT, int NT>
__global__ __launch_bounds__(512, 2) void gemm256(
    const unsigned short* __restrict__ A,
    const unsigned short* __restrict__ Bw,
    OutT* __restrict__ C, int M, int N)
{
  constexpr int K  = 4096;
  constexpr int NI = (K / 64) / 2;     // 32 iterations, 2 K-tiles each
  constexpr int NB = NT / 64;          // B chunks per tile (3 or 4)
  constexpr int NN = NT / 64;          // n-frags per wave
  constexpr int WN = NT / 4;           // per-wave N extent
  constexpr int BBUF = NT * 128;       // B bytes per buffer
  __shared__ __align__(16) char lds[65536 + 2 * BBUF];

  const int tid  = threadIdx.x;
  const int lane = tid & 63;
  const int wave = tid >> 6;
  const int wr = wave >> 2;            // 0..1  (M half)
  const int wc = wave & 3;             // 0..3  (N quarter)
  const int lr = lane & 15;
  const int lk = (lane >> 4) * 8;

  int id  = blockIdx.y * gridDim.x + blockIdx.x;
  const int nwg = gridDim.x * gridDim.y;
  if ((nwg & 7) == 0) { const int q = nwg >> 3; id = (id & 7) * q + (id >> 3); }
  const int row0 = (id / gridDim.x) * 256;
  const int col0 = (id % gridDim.x) * NT;

  // A staging: 2 halves x 2 loads/thread (16KB each).
  int rwA[2], csA[2], dbA[2];
#pragma unroll
  for (int j = 0; j < 2; ++j) {
    dbA[j] = j * 8192 + tid * 16;
    rwA[j] = dbA[j] >> 7;
    csA[j] = ((dbA[j] & 127) ^ ((rwA[j] & 7) << 4)) >> 1;
  }
  auto stA = [&](int buf, int h, int t) {
#pragma unroll
    for (int j = 0; j < 2; ++j)
      cp16(A + (size_t)(row0 + h * 128 + rwA[j]) * K + t * 64 + csA[j],
           lds + buf * 32768 + h * 16384 + dbA[j]);
  };
  // B staging: NB chunks x 1 load/thread (8KB each, 64 rows).
  const int dbB = tid * 16;
  const int rwB = dbB >> 7;                              // 0..63
  const int csB = ((dbB & 127) ^ ((rwB & 7) << 4)) >> 1; // chunk row base %8==0
  auto stB = [&](int buf, int c, int t) {
    cp16(Bw + (size_t)(col0 + c * 64 + rwB) * K + t * 64 + csB,
         lds + 65536 + buf * BBUF + c * 8192 + dbB);
  };

  const int cb0 = ((0 + lk) << 1) ^ ((lr & 7) << 4);
  const int cb1 = ((32 + lk) << 1) ^ ((lr & 7) << 4);
  const int aRowB = (wr * 128 + lr) * 128;
  const int bRowB = (wc * WN + lr) * 128;

  f32x4 acc[8][NN];
#pragma unroll
  for (int m = 0; m < 8; ++m)
#pragma unroll
    for (int n = 0; n < NN; ++n) acc[m][n] = (f32x4){0.f, 0.f, 0.f, 0.f};
  bf16x8 bfr[NN][2];

#define FENCE asm volatile("" ::: "memory")
#define VMNB  do { if constexpr (NB == 4) asm volatile("s_waitcnt vmcnt(4)" ::: "memory"); \
                   else                   asm volatile("s_waitcnt vmcnt(3)" ::: "memory"); } while (0)
#define VM0   asm volatile("s_waitcnt vmcnt(0)" ::: "memory")

#define PHASE(p, buf, STAGE, WAIT)                                             \
  {                                                                            \
    if ((p) == 0) {                                                            \
      _Pragma("unroll")                                                        \
      for (int n = 0; n < NN; ++n) {                                           \
        bfr[n][0] = ld8b(lds, 65536 + (buf) * BBUF + bRowB + n * 2048 + cb0);  \
        bfr[n][1] = ld8b(lds, 65536 + (buf) * BBUF + bRowB + n * 2048 + cb1);  \
      }                                                                        \
    }                                                                          \
    bf16x8 a00 = ld8b(lds, (buf) * 32768 + aRowB + ((p) * 2 + 0) * 2048 + cb0);\
    bf16x8 a01 = ld8b(lds, (buf) * 32768 + aRowB + ((p) * 2 + 0) * 2048 + cb1);\
    bf16x8 a10 = ld8b(lds, (buf) * 32768 + aRowB + ((p) * 2 + 1) * 2048 + cb0);\
    bf16x8 a11 = ld8b(lds, (buf) * 32768 + aRowB + ((p) * 2 + 1) * 2048 + cb1);\
    STAGE;                                                                     \
    FENCE;                                                                     \
    __builtin_amdgcn_s_barrier();                                              \
    __builtin_amdgcn_s_setprio(1);                                             \
    _Pragma("unroll")                                                          \
    for (int n = 0; n < NN; ++n) {                                             \
      acc[(p)*2+0][n] = __builtin_amdgcn_mfma_f32_16x16x32_bf16(a00, bfr[n][0], acc[(p)*2+0][n], 0, 0, 0); \
      acc[(p)*2+0][n] = __builtin_amdgcn_mfma_f32_16x16x32_bf16(a01, bfr[n][1], acc[(p)*2+0][n], 0, 0, 0); \
      acc[(p)*2+1][n] = __builtin_amdgcn_mfma_f32_16x16x32_bf16(a10, bfr[n][0], acc[(p)*2+1][n], 0, 0, 0); \
      acc[(p)*2+1][n] = __builtin_amdgcn_mfma_f32_16x16x32_bf16(a11, bfr[n][1], acc[(p)*2+1][n], 0, 0, 0); \
    }                                                                          \
    __builtin_amdgcn_s_setprio(0);                                             \
    WAIT;                                                                      \
    FENCE;                                                                     \
    __builtin_amdgcn_s_barrier();                                              \
  }

  // Prologue: tile0 B+A into buf0, tile1 B into buf1; allow tile1-B in flight.
#pragma unroll
  for (int c = 0; c < NB; ++c) stB(0, c, 0);
  stA(0, 0, 0); stA(0, 1, 0);
#pragma unroll
  for (int c = 0; c < NB; ++c) stB(1, c, 1);
  VMNB;
  FENCE;
  __builtin_amdgcn_s_barrier();

  for (int i = 0; i < NI; ++i) {
    const int t1  = 2 * i + 1;
    const int tn0 = 2 * i + 2;
    const int tn1 = 2 * i + 3;
    const bool pre = (i + 1 < NI);
    // K-tile 2i in buf0
    PHASE(0, 0, { stA(1, 0, t1); }, {});
    PHASE(1, 0, { stA(1, 1, t1); }, {});
    PHASE(2, 0, { if (pre) { stB(0, 0, tn0); stB(0, 1, tn0); } }, {});
    PHASE(3, 0, { if (pre) { _Pragma("unroll") for (int c = 2; c < NB; ++c) stB(0, c, tn0); } },
          { if (pre) { VMNB; } else { VM0; } });
    // K-tile 2i+1 in buf1
    PHASE(0, 1, { if (pre) stA(0, 0, tn0); }, {});
    PHASE(1, 1, { if (pre) stA(0, 1, tn0); }, {});
    PHASE(2, 1, { if (pre) { stB(1, 0, tn1); stB(1, 1, tn1); } }, {});
    PHASE(3, 1, { if (pre) { _Pragma("unroll") for (int c = 2; c < NB; ++c) stB(1, c, tn1); } },
          { if (pre) { VMNB; } });
  }
#undef PHASE
#undef FENCE
#undef VMNB
#undef VM0

  const int orow = (lane >> 4) * 4;
#pragma unroll
  for (int m = 0; m < 8; ++m) {
    const int gr0 = row0 + wr * 128 + m * 16 + orow;
#pragma unroll
    for (int n = 0; n < NN; ++n) {
      const int gc = col0 + wc * WN + n * 16 + lr;
#pragma unroll
      for (int r = 0; r < 4; ++r) {
        float val = acc[m][n][r];
        if constexpr (sizeof(OutT) == 2)
          C[(size_t)(gr0 + r) * N + gc] = f2bf(val);
        else
          C[(size_t)(gr0 + r) * N + gc] = val;
      }
    }
  }
}

// ---------------------------------------------------------------------------
// Split fused[B,S,48,128] into Qr (rope), Kr (rope), Vt (transposed).
// ---------------------------------------------------------------------------
__global__ __launch_bounds__(256) void rope_scatter(
    const unsigned short* __restrict__ fused,
    unsigned short* __restrict__ Qr,
    unsigned short* __restrict__ Kr,
    unsigned short* __restrict__ Vt)
{
  int idx = blockIdx.x * 256 + threadIdx.x;  // [0, B*S*48*64)
  int d = idx & 63;
  int t = idx >> 6;
  int e = t % 48;
  int bs = t / 48;
  int s = bs % S_;
  int b = bs / S_;
  int kvh = e / 6, j = e % 6;
  const unsigned short* src = fused + (size_t)bs * NE_ + e * 128;
  unsigned short u1 = src[d];
  unsigned short u2 = src[d + 64];
  if (j == 5) {
    size_t base = (size_t)(b * KVH_ + kvh) * HD_ * S_;
    Vt[base + (size_t)d * S_ + s]        = u1;
    Vt[base + (size_t)(d + 64) * S_ + s] = u2;
  } else {
    float x1 = bf2f(u1), x2 = bf2f(u2);
    float inv = __expf(-(float)d * (9.2103403719761836f / 64.0f));
    float ang = (float)s * inv;
    float sn, c;
    sincosf(ang, &sn, &c);
    float o1 = x1 * c - x2 * sn;
    float o2 = x2 * c + x1 * sn;
    unsigned short* dst;
    if (j == 4) dst = Kr + ((size_t)(b * KVH_ + kvh) * S_ + s) * HD_;
    else        dst = Qr + ((size_t)(b * H_ + kvh * 4 + j) * S_ + s) * HD_;
    dst[d]      = f2bf(o1);
    dst[d + 64] = f2bf(o2);
  }
}

// ---------------------------------------------------------------------------
// Causal GQA flash attention. Round-9 staging (K/V dbuf, prefetch-first) kept;
// softmax critical path cut:
//  - log2-domain scores: Q pre-scaled by scale*log2e, p = exp2(s - m) (v_exp)
//  - per-lane lrow PARTIALS (no per-iter sum butterflies; 1 reduce at end)
//  - defer-max (T13, THR=8 log2): in-lane kt-max + __all; cross-lane max
//    reduce + acc_o/lrow rescale only when running max grows
//  - causal mask only in the block-uniform last iteration
// ---------------------------------------------------------------------------
__global__ __launch_bounds__(256) void attn_fwd(
    const unsigned short* __restrict__ Qr,
    const unsigned short* __restrict__ Kr,
    const unsigned short* __restrict__ Vt,
    unsigned short* __restrict__ O)
{
  __shared__ __align__(16) unsigned short Kld[2][64 * 128];
  __shared__ __align__(16) unsigned short Vld[2][128 * 64];
  __shared__ __align__(16) unsigned short Pld[4][16 * 64];

  const int tid  = threadIdx.x;
  const int lane = tid & 63;
  const int wave = tid >> 6;
  const int bx = blockIdx.x;   // 0..15
  const int h  = blockIdx.y;   // 0..31
  const int b  = blockIdx.z;   // 0..1
  const int kvh = h >> 2;
  const int lr = lane & 15;
  const int lk = (lane >> 4) * 8;
  const int orow = (lane >> 4) * 4;

  const float SC2 = 0.08838834764831845f * 1.4426950408889634f; // scale*log2e
  const unsigned short* Kb = Kr + (size_t)(b * KVH_ + kvh) * S_ * HD_;
  const unsigned short* Vb = Vt + (size_t)(b * KVH_ + kvh) * HD_ * S_;

  auto stage = [&](int buf, int kb) {
#pragma unroll
    for (int i = 0; i < 4; ++i) {
      const int db = i * 4096 + tid * 16;
      {  // K: 256 B/row
        const int row  = db >> 8;
        const int colb = (db & 255) ^ ((row & 7) << 4);
        cp16(Kb + (size_t)(kb * 64 + row) * HD_ + (colb >> 1),
             (char*)&Kld[buf][0] + i * 4096 + wave * 1024);
      }
      {  // V: 128 B/row
        const int row  = db >> 7;
        const int colb = (db & 127) ^ ((row & 7) << 4);
        cp16(Vb + (size_t)row * S_ + kb * 64 + (colb >> 1),
             (char*)&Vld[buf][0] + i * 4096 + wave * 1024);
      }
    }
  };

  for (int half = 0; half < 2; ++half) {
    const int qb = half ? (S_ / 64 - 1 - bx) : bx;

    const unsigned short* qbase =
        Qr + ((size_t)(b * H_ + h) * S_ + qb * 64 + wave * 16 + lr) * HD_;
    bf16x8 qf[4];
#pragma unroll
    for (int t = 0; t < 4; ++t) {
      union { bf16x8 v; unsigned short s[8]; } u;
      u.v = ld8(qbase + t * 32 + lk);
#pragma unroll
      for (int j = 0; j < 8; ++j) u.s[j] = f2bf(bf2f(u.s[j]) * SC2);
      qf[t] = u.v;
    }

    f32x4 acc_o[8];
#pragma unroll
    for (int dt = 0; dt < 8; ++dt) acc_o[dt] = (f32x4){0.f, 0.f, 0.f, 0.f};
    float mrow[4], lpart[4];
#pragma unroll
    for (int r = 0; r < 4; ++r) { mrow[r] = -1e30f; lpart[r] = 0.f; }

    stage(0, 0);
    __syncthreads();

    for (int kb = 0; kb <= qb; ++kb) {
      const int cur = kb & 1;
      if (kb < qb) stage(cur ^ 1, kb + 1);   // prefetch next tile FIRST

      const char* Kc = (const char*)&Kld[cur][0];
      const char* Vc = (const char*)&Vld[cur][0];

      // S = (scale*log2e) * Q K^T  (scale folded into Q)
      f32x4 accs[4];
#pragma unroll
      for (int kt = 0; kt < 4; ++kt) accs[kt] = (f32x4){0.f, 0.f, 0.f, 0.f};
      __builtin_amdgcn_s_setprio(1);
#pragma unroll
      for (int t = 0; t < 4; ++t) {
#pragma unroll
        for (int kt = 0; kt < 4; ++kt) {
          const int krow = kt * 16 + lr;
          const int kbyte = ((krow << 8) + ((t * 32 + lk) << 1)) ^ ((krow & 7) << 4);
          bf16x8 kf = ld8b(Kc, kbyte);
          accs[kt] = __builtin_amdgcn_mfma_f32_16x16x32_bf16(qf[t], kf, accs[kt], 0, 0, 0);
        }
      }
      __builtin_amdgcn_s_setprio(0);

      if (kb == qb) {  // block-uniform: mask only in the diagonal tile
#pragma unroll
        for (int r = 0; r < 4; ++r) {
          const int qg = wave * 16 + orow + r;
#pragma unroll
          for (int kt = 0; kt < 4; ++kt)
            if (kt * 16 + lr > qg) accs[kt][r] = -1e30f;
        }
      }

      // in-lane kt-max; defer-check without cross-lane reduce
      float mx[4];
#pragma unroll
      for (int r = 0; r < 4; ++r)
        mx[r] = fmaxf(fmaxf(accs[0][r], accs[1][r]), fmaxf(accs[2][r], accs[3][r]));
      int ok = (mx[0] <= mrow[0] + 8.f) && (mx[1] <= mrow[1] + 8.f) &&
               (mx[2] <= mrow[2] + 8.f) && (mx[3] <= mrow[3] + 8.f);
      if (!__all(ok)) {   // rare: running max grew; full rescale
        float corr[4];
#pragma unroll
        for (int r = 0; r < 4; ++r) {
          float m = mx[r];
#pragma unroll
          for (int msk = 8; msk >= 1; msk >>= 1) m = fmaxf(m, __shfl_xor(m, msk, 64));
          float mnew = fmaxf(mrow[r], m);
          corr[r] = exp2a(mrow[r] - mnew);
          mrow[r] = mnew;
          lpart[r] *= corr[r];
        }
#pragma unroll
        for (int dt = 0; dt < 8; ++dt)
#pragma unroll
          for (int r = 0; r < 4; ++r) acc_o[dt][r] *= corr[r];
      }

      // p = exp2(s - m); accumulate per-lane partials; store bf16 P
#pragma unroll
      for (int r = 0; r < 4; ++r) {
        const int prow = orow + r;
#pragma unroll
        for (int kt = 0; kt < 4; ++kt) {
          float p = exp2a(accs[kt][r] - mrow[r]);
          lpart[r] += p;
          const int pbyte = ((prow << 7) + ((kt * 16 + lr) << 1)) ^ ((prow & 7) << 4);
          *(__bf16*)((char*)&Pld[wave][0] + pbyte) = (__bf16)p;
        }
      }

      asm volatile("" ::: "memory");  // Pld ushort-write vs bf16x8-read (TBAA)

      // O += P V
      __builtin_amdgcn_s_setprio(1);
#pragma unroll
      for (int kc = 0; kc < 2; ++kc) {
        const int pbyte = ((lr << 7) + ((kc * 32 + lk) << 1)) ^ ((lr & 7) << 4);
        bf16x8 pf = ld8b(&Pld[wave][0], pbyte);
#pragma unroll
        for (int dt = 0; dt < 8; ++dt) {
          const int vrow = dt * 16 + lr;
          const int vbyte = ((vrow << 7) + ((kc * 32 + lk) << 1)) ^ ((vrow & 7) << 4);
          bf16x8 vf = ld8b(Vc, vbyte);
          acc_o[dt] = __builtin_amdgcn_mfma_f32_16x16x32_bf16(pf, vf, acc_o[dt], 0, 0, 0);
        }
      }
      __builtin_amdgcn_s_setprio(0);

      __syncthreads();  // lands prefetch + separates buffer reuse
    }

    // one cross-lane sum reduce at the end (was per-iteration)
#pragma unroll
    for (int r = 0; r < 4; ++r) {
      float s = lpart[r];
#pragma unroll
      for (int msk = 8; msk >= 1; msk >>= 1) s += __shfl_xor(s, msk, 64);
      float inv = 1.f / s;
      size_t rowoff =
          (size_t)(b * S_ + qb * 64 + wave * 16 + orow + r) * (H_ * HD_) + h * HD_;
#pragma unroll
      for (int dt = 0; dt < 8; ++dt)
        O[rowoff + dt * 16 + lr] = f2bf(acc_o[dt][r] * inv);
    }
  }
}

// Diagnostic: if ws_size is too small, fill fp32 output with sentinel 12345.
__global__ void fill_sentinel(float* __restrict__ O, int n) {
  int i = blockIdx.x * 256 + threadIdx.x;
  if (i < n) O[i] = 12345.0f;
}

// ---------------------------------------------------------------------------
extern "C" void kernel_launch(void* const* d_in, const int* in_sizes, int n_in,
                              void* d_out, int out_size, void* d_ws, size_t ws_size,
                              hipStream_t stream) {
  const float* hidden = (const float*)d_in[0]; // [B,S,D] fp32
  const float* wqkv   = (const float*)d_in[1]; // [6144,4096] fp32
  const float* wdense = (const float*)d_in[2]; // [4096,4096] fp32
  float* out = (float*)d_out;                  // [B,S,4096] fp32

  const size_t NEED = 134217728;
  if (ws_size < NEED) {
    fill_sentinel<<<dim3((out_size + 255) / 256), dim3(256), 0, stream>>>(out, out_size);
    return;
  }

  char* ws = (char*)d_ws;
  // Phase 1 layout
  unsigned short* Hb    = (unsigned short*)(ws);                 // 33,554,432 B
  unsigned short* Wqb   = (unsigned short*)(ws + 33554432);      // 50,331,648 B
  unsigned short* fused = (unsigned short*)(ws + 83886080);      // 50,331,648 B
  // Phase 2 layout (after GEMM1: Hb/Wqb dead; Wdb sequenced AFTER GEMM1!)
  unsigned short* Qr    = (unsigned short*)(ws);                 // 33,554,432 B
  unsigned short* Kr    = (unsigned short*)(ws + 33554432);      //  8,388,608 B
  unsigned short* Vt    = (unsigned short*)(ws + 41943040);      //  8,388,608 B
  unsigned short* Wdb   = (unsigned short*)(ws + 50331648);      // 33,554,432 B
  unsigned short* attn_out = (unsigned short*)(ws + 83886080);   // 33,554,432 B (over fused)

  const int nH4 = B_ * S_ * D_ / 4;   // 4,194,304
  const int nQ4 = NE_ * D_ / 4;       // 6,291,456
  const int nD4 = D_ * D_ / 4;        // 4,194,304

  cvt2_f32_bf16<<<dim3((nH4 + nQ4 + 255) / 256), dim3(256), 0, stream>>>(
      hidden, Hb, nH4, wqkv, Wqb, nQ4);

  gemm256<unsigned short, 192><<<dim3(NE_ / 192, (B_ * S_) / 256), dim3(512), 0, stream>>>(
      Hb, Wqb, fused, B_ * S_, NE_);

  cvt_f32_bf16<<<dim3(nD4 / 256), dim3(256), 0, stream>>>(wdense, Wdb, nD4);

  rope_scatter<<<dim3((B_ * S_ * 48 * 64) / 256), dim3(256), 0, stream>>>(
      fused, Qr, Kr, Vt);

  attn_fwd<<<dim3(16, H_, B_), dim3(256), 0, stream>>>(Qr, Kr, Vt, attn_out);

  gemm256<float, 256><<<dim3(D_ / 256, (B_ * S_) / 256), dim3(512), 0, stream>>>(
      attn_out, Wdb, out, B_ * S_, D_);
}